// Round 22
// baseline (2958.312 us; speedup 1.0000x reference)
//
#include <hip/hip_runtime.h>
#include <cstddef>

#define NROWS 16385
#define NPAD  16640
#define PADT  255
#define DIM   512
#define HEADS 8
#define DH    64
#define NL    256
#define LCH   65
#define LCHUNK 65
#define SLACK 24
#define LDST  40   // padded LDS row stride (ushorts) for MFMA gemm tiles
#define AST   72   // attn3/lattn3 LDS row stride (ushorts); 144B = 16B-aligned rows

typedef short bf16x8 __attribute__((ext_vector_type(8)));
typedef float f32x4  __attribute__((ext_vector_type(4)));

__device__ __forceinline__ float wsum(float v){
#pragma unroll
  for (int o = 32; o; o >>= 1) v += __shfl_xor(v, o);
  return v;
}
__device__ __forceinline__ float wmax(float v){
#pragma unroll
  for (int o = 32; o; o >>= 1) v = fmaxf(v, __shfl_xor(v, o));
  return v;
}

// bijective XCD-chunked block remap (m204)
__device__ __forceinline__ int xcd_swz(int orig, int nwg){
  int q = nwg >> 3, r = nwg & 7;
  int x = orig & 7, j = orig >> 3;
  return (x < r ? x*(q+1) : r*(q+1) + (x-r)*q) + j;
}

// split fp32 -> (hi bf16, lo bf16) with RNE
__device__ __forceinline__ void split2(float x, unsigned short &h, unsigned short &l){
  unsigned ux = __float_as_uint(x);
  unsigned rh = (ux + 0x7FFFu + ((ux >> 16) & 1u)) >> 16;
  h = (unsigned short)rh;
  float fh = __uint_as_float(rh << 16);
  float r = x - fh;
  unsigned ur = __float_as_uint(r);
  unsigned rl = (ur + 0x7FFFu + ((ur >> 16) & 1u)) >> 16;
  l = (unsigned short)rl;
}
__device__ __forceinline__ float bf2f(unsigned short h){
  return __uint_as_float((unsigned)h << 16);
}

// device-scope grid barrier (cumulative counter, 128 co-resident blocks)
__device__ __forceinline__ void gbar(unsigned* bar, unsigned target){
  __threadfence();            // drain this thread's stores to L2
  __syncthreads();            // all threads of block drained
  if (threadIdx.x == 0){
    atomicAdd(bar, 1u);
    while (atomicAdd(bar, 0u) < target) __builtin_amdgcn_s_sleep(2);
  }
  __syncthreads();
  __threadfence();            // invalidate L1 before reading peers' data
}

// ---------------- 64x64 batched MFMA GEMM on pre-split bf16 planes ----------------
// epilogue: v = aAcc*acc + cDiag*(row==col) + c1*rec(IB1) + c2*rec(IB2)
__global__ __launch_bounds__(256) void gemm64_sp_kernel(
    const unsigned short* __restrict__ Ah, const unsigned short* __restrict__ Al,
    const unsigned short* __restrict__ Bth, const unsigned short* __restrict__ Btl,
    const unsigned short* __restrict__ IB1h, const unsigned short* __restrict__ IB1l,
    const unsigned short* __restrict__ IB2h, const unsigned short* __restrict__ IB2l,
    float* __restrict__ Cf,
    unsigned short* __restrict__ Crh, unsigned short* __restrict__ Crl,
    unsigned short* __restrict__ Cth, unsigned short* __restrict__ Ctl,
    int M, int N, int K, long sA, long sB, long sC,
    float aAcc, float cDiag, float c1, float c2)
{
  size_t zo = (size_t)blockIdx.z;
  Ah  += zo*sA; Al  += zo*sA;
  Bth += zo*sB; Btl += zo*sB;
  if (IB1h){ IB1h += zo*sA; IB1l += zo*sA; }
  if (IB2h){ IB2h += zo*sA; IB2l += zo*sA; }
  if (Cf)  Cf  += zo*sC;
  if (Crh){ Crh += zo*sC; Crl += zo*sC; }
  if (Cth){ Cth += zo*sC; Ctl += zo*sC; }
  __shared__ unsigned short LAh[64*LDST], LAl[64*LDST], LBh[64*LDST], LBl[64*LDST];
  const int t = threadIdx.x;
  const int wid = t >> 6, lane = t & 63;
  const int wr = wid >> 1, wc = wid & 1;
  const int l15 = lane & 15, kb = lane >> 4;
  const int bm = blockIdx.y << 6, bn = blockIdx.x << 6;
  const int r4 = t >> 2, kc = (t & 3) << 3;
  f32x4 acc[2][2];
#pragma unroll
  for (int i=0;i<2;++i)
#pragma unroll
    for (int j=0;j<2;++j) acc[i][j] = (f32x4){0.f,0.f,0.f,0.f};

  for (int k0 = 0; k0 < K; k0 += 32){
    __syncthreads();
    {
      int lo = r4*LDST + kc;
      *(uint4*)&LAh[lo] = *(const uint4*)&Ah[(size_t)(bm+r4)*K + k0 + kc];
      *(uint4*)&LAl[lo] = *(const uint4*)&Al[(size_t)(bm+r4)*K + k0 + kc];
      *(uint4*)&LBh[lo] = *(const uint4*)&Bth[(size_t)(bn+r4)*K + k0 + kc];
      *(uint4*)&LBl[lo] = *(const uint4*)&Btl[(size_t)(bn+r4)*K + k0 + kc];
    }
    __syncthreads();
    bf16x8 ah[2], al[2], bh[2], bl[2];
#pragma unroll
    for (int r=0;r<2;++r){
      int off = (wr*32 + r*16 + l15)*LDST + kb*8;
      ah[r] = *(const bf16x8*)&LAh[off];
      al[r] = *(const bf16x8*)&LAl[off];
    }
#pragma unroll
    for (int c2v=0;c2v<2;++c2v){
      int off = (wc*32 + c2v*16 + l15)*LDST + kb*8;
      bh[c2v] = *(const bf16x8*)&LBh[off];
      bl[c2v] = *(const bf16x8*)&LBl[off];
    }
#pragma unroll
    for (int r=0;r<2;++r)
#pragma unroll
      for (int c2v=0;c2v<2;++c2v){
        acc[r][c2v] = __builtin_amdgcn_mfma_f32_16x16x32_bf16(ah[r], bh[c2v], acc[r][c2v], 0,0,0);
        acc[r][c2v] = __builtin_amdgcn_mfma_f32_16x16x32_bf16(ah[r], bl[c2v], acc[r][c2v], 0,0,0);
        acc[r][c2v] = __builtin_amdgcn_mfma_f32_16x16x32_bf16(al[r], bh[c2v], acc[r][c2v], 0,0,0);
      }
  }
#pragma unroll
  for (int r=0;r<2;++r){
#pragma unroll
    for (int c2v=0;c2v<2;++c2v){
      int col = bn + wc*32 + c2v*16 + l15;
      int rb  = bm + wr*32 + r*16 + kb*4;
      float v[4];
#pragma unroll
      for (int e=0;e<4;++e){
        float x = aAcc*acc[r][c2v][e];
        int row = rb + e;
        if (cDiag != 0.f && row == col) x += cDiag;
        if (IB1h){
          size_t io = (size_t)row*K + col;
          x += c1*(bf2f(IB1h[io]) + bf2f(IB1l[io]));
        }
        if (IB2h){
          size_t io = (size_t)row*K + col;
          x += c2*(bf2f(IB2h[io]) + bf2f(IB2l[io]));
        }
        v[e] = x;
      }
      if (Cf){
#pragma unroll
        for (int e=0;e<4;++e) Cf[(size_t)(rb+e)*N + col] = v[e];
      }
      if (Crh){
#pragma unroll
        for (int e=0;e<4;++e){
          unsigned short hh, ll;
          split2(v[e], hh, ll);
          Crh[(size_t)(rb+e)*N + col] = hh;
          Crl[(size_t)(rb+e)*N + col] = ll;
        }
      }
      if (Cth){
        unsigned short h4[4], l4[4];
#pragma unroll
        for (int e=0;e<4;++e) split2(v[e], h4[e], l4[e]);
        uint2 uh, ul;
        uh.x = (unsigned)h4[0] | ((unsigned)h4[1]<<16);
        uh.y = (unsigned)h4[2] | ((unsigned)h4[3]<<16);
        ul.x = (unsigned)l4[0] | ((unsigned)l4[1]<<16);
        ul.y = (unsigned)l4[2] | ((unsigned)l4[3]<<16);
        *(uint2*)&Cth[(size_t)col*M + rb] = uh;
        *(uint2*)&Ctl[(size_t)col*M + rb] = ul;
      }
    }
  }
}

// -------- one pinv GEMM stage (M=N=K=256, z-stride 65536), for the fused kernel
__device__ void pinv_stage(
    const unsigned short* Ah, const unsigned short* Al,
    const unsigned short* Bth, const unsigned short* Btl,
    const unsigned short* IBh, const unsigned short* IBl,
    unsigned short* Crh, unsigned short* Crl,
    unsigned short* Cth, unsigned short* Ctl,
    float aAcc, float c1, int bx, int by, int bz)
{
  __shared__ unsigned short LAh[64*LDST], LAl[64*LDST], LBh[64*LDST], LBl[64*LDST];
  const size_t zo = (size_t)bz * 65536;
  Ah += zo; Al += zo; Bth += zo; Btl += zo;
  if (IBh){ IBh += zo; IBl += zo; }
  if (Crh){ Crh += zo; Crl += zo; }
  if (Cth){ Cth += zo; Ctl += zo; }
  const int t = threadIdx.x;
  const int wid = t >> 6, lane = t & 63;
  const int wr = wid >> 1, wc = wid & 1;
  const int l15 = lane & 15, kb = lane >> 4;
  const int bm = by << 6, bn = bx << 6;
  const int r4 = t >> 2, kc = (t & 3) << 3;
  f32x4 acc[2][2];
#pragma unroll
  for (int i=0;i<2;++i)
#pragma unroll
    for (int j=0;j<2;++j) acc[i][j] = (f32x4){0.f,0.f,0.f,0.f};

  for (int k0 = 0; k0 < 256; k0 += 32){
    __syncthreads();
    {
      int lo = r4*LDST + kc;
      *(uint4*)&LAh[lo] = *(const uint4*)&Ah[(size_t)(bm+r4)*256 + k0 + kc];
      *(uint4*)&LAl[lo] = *(const uint4*)&Al[(size_t)(bm+r4)*256 + k0 + kc];
      *(uint4*)&LBh[lo] = *(const uint4*)&Bth[(size_t)(bn+r4)*256 + k0 + kc];
      *(uint4*)&LBl[lo] = *(const uint4*)&Btl[(size_t)(bn+r4)*256 + k0 + kc];
    }
    __syncthreads();
    bf16x8 ah[2], al[2], bh[2], bl[2];
#pragma unroll
    for (int r=0;r<2;++r){
      int off = (wr*32 + r*16 + l15)*LDST + kb*8;
      ah[r] = *(const bf16x8*)&LAh[off];
      al[r] = *(const bf16x8*)&LAl[off];
    }
#pragma unroll
    for (int c2v=0;c2v<2;++c2v){
      int off = (wc*32 + c2v*16 + l15)*LDST + kb*8;
      bh[c2v] = *(const bf16x8*)&LBh[off];
      bl[c2v] = *(const bf16x8*)&LBl[off];
    }
#pragma unroll
    for (int r=0;r<2;++r)
#pragma unroll
      for (int c2v=0;c2v<2;++c2v){
        acc[r][c2v] = __builtin_amdgcn_mfma_f32_16x16x32_bf16(ah[r], bh[c2v], acc[r][c2v], 0,0,0);
        acc[r][c2v] = __builtin_amdgcn_mfma_f32_16x16x32_bf16(ah[r], bl[c2v], acc[r][c2v], 0,0,0);
        acc[r][c2v] = __builtin_amdgcn_mfma_f32_16x16x32_bf16(al[r], bh[c2v], acc[r][c2v], 0,0,0);
      }
  }
#pragma unroll
  for (int r=0;r<2;++r){
#pragma unroll
    for (int c2v=0;c2v<2;++c2v){
      int col = bn + wc*32 + c2v*16 + l15;
      int rb  = bm + wr*32 + r*16 + kb*4;
      float v[4];
#pragma unroll
      for (int e=0;e<4;++e){
        float x = aAcc*acc[r][c2v][e];
        if (IBh){
          size_t io = (size_t)(rb+e)*256 + col;
          x += c1*(bf2f(IBh[io]) + bf2f(IBl[io]));
        }
        v[e] = x;
      }
      if (Crh){
#pragma unroll
        for (int e=0;e<4;++e){
          unsigned short hh, ll;
          split2(v[e], hh, ll);
          Crh[(size_t)(rb+e)*256 + col] = hh;
          Crl[(size_t)(rb+e)*256 + col] = ll;
        }
      }
      if (Cth){
        unsigned short h4[4], l4[4];
#pragma unroll
        for (int e=0;e<4;++e) split2(v[e], h4[e], l4[e]);
        uint2 uh, ul;
        uh.x = (unsigned)h4[0] | ((unsigned)h4[1]<<16);
        uh.y = (unsigned)h4[2] | ((unsigned)h4[3]<<16);
        ul.x = (unsigned)l4[0] | ((unsigned)l4[1]<<16);
        ul.y = (unsigned)l4[2] | ((unsigned)l4[3]<<16);
        *(uint2*)&Cth[(size_t)col*256 + rb] = uh;
        *(uint2*)&Ctl[(size_t)col*256 + rb] = ul;
      }
    }
  }
}

// -------- fused 6-iteration Newton-Schulz chain; grid 128 blocks (co-resident), block 256
__global__ __launch_bounds__(256) void pinv_fused_kernel(
    const unsigned short* __restrict__ A2h, const unsigned short* __restrict__ A2l,
    unsigned short* __restrict__ XZrh, unsigned short* __restrict__ XZrl,
    unsigned short* __restrict__ XZth, unsigned short* __restrict__ XZtl,
    unsigned short* __restrict__ Wth,  unsigned short* __restrict__ Wtl,
    unsigned short* __restrict__ W2th, unsigned short* __restrict__ W2tl,
    unsigned short* __restrict__ Z0rh, unsigned short* __restrict__ Z0rl,
    unsigned short* __restrict__ Z0th, unsigned short* __restrict__ Z0tl,
    unsigned short* __restrict__ Z1rh, unsigned short* __restrict__ Z1rl,
    unsigned short* __restrict__ Z1th, unsigned short* __restrict__ Z1tl,
    unsigned* __restrict__ bar)
{
  const int blk = blockIdx.x;
  const int bx = blk & 3, by = (blk >> 2) & 3, bz = blk >> 4;
  unsigned short *Zarh=Z0rh, *Zarl=Z0rl, *Zath=Z0th, *Zatl=Z0tl;
  unsigned short *Zbrh=Z1rh, *Zbrl=Z1rl, *Zbth=Z1th, *Zbtl=Z1tl;
  unsigned tgt = 0;
  for (int it = 0; it < 6; ++it){
    // M = A2 @ Za  (rm -> XZr, tp -> XZt)
    pinv_stage(A2h,A2l, Zath,Zatl, nullptr,nullptr,
               XZrh,XZrl, XZth,XZtl, 1.f, 0.f, bx,by,bz);
    tgt += 128; gbar(bar, tgt);
    // W = 7M - M@M  (tp -> Wt)
    pinv_stage(XZrh,XZrl, XZth,XZtl, XZrh,XZrl,
               nullptr,nullptr, Wth,Wtl, -1.f, 7.f, bx,by,bz);
    tgt += 128; gbar(bar, tgt);
    // W2 = 15M - M@W  (tp -> W2t)
    pinv_stage(XZrh,XZrl, Wth,Wtl, XZrh,XZrl,
               nullptr,nullptr, W2th,W2tl, -1.f, 15.f, bx,by,bz);
    tgt += 128; gbar(bar, tgt);
    // Zb = 3.25*Za - 0.25*Za@W2  (rm + tp -> Zb)
    pinv_stage(Zarh,Zarl, W2th,W2tl, Zarh,Zarl,
               Zbrh,Zbrl, Zbth,Zbtl, -0.25f, 3.25f, bx,by,bz);
    unsigned short* tp;
    tp=Zarh; Zarh=Zbrh; Zbrh=tp;  tp=Zarl; Zarl=Zbrl; Zbrl=tp;
    tp=Zath; Zath=Zbth; Zbth=tp;  tp=Zatl; Zatl=Zbtl; Zbtl=tp;
    if (it < 5){ tgt += 128; gbar(bar, tgt); }
  }
  // 6 swaps (even) -> final Za lives in Z0 buffers
}

// ---------------- split-bf16 MFMA GEMM: pre-split A planes (XCD-swizzled) ----------------
__global__ __launch_bounds__(256) void gemm_sb_kernel(
    const unsigned short* __restrict__ Ah, const unsigned short* __restrict__ Al,
    const unsigned short* __restrict__ BTh, const unsigned short* __restrict__ BTl,
    const float* __restrict__ bias, float* __restrict__ C,
    int M, int N, int K, int accum)
{
  __shared__ unsigned short LAh[128*LDST], LAl[128*LDST], LBh[128*LDST], LBl[128*LDST];
  const int t = threadIdx.x;
  const int nwg = gridDim.x * gridDim.y;
  const int orig = blockIdx.y * gridDim.x + blockIdx.x;
  const int wgid = xcd_swz(orig, nwg);
  const int bxi = wgid % gridDim.x, byi = wgid / gridDim.x;
  const int bm = byi << 7, bn = bxi << 7;
  const int wid = t >> 6, lane = t & 63;
  const int wr = wid >> 1, wc = wid & 1;
  const int l15 = lane & 15, kb = lane >> 4;
  const int sr = t >> 1, sc0 = (t & 1) << 4;
  f32x4 acc[4][4];
#pragma unroll
  for (int i=0;i<4;++i)
#pragma unroll
    for (int j=0;j<4;++j) acc[i][j] = (f32x4){0.f,0.f,0.f,0.f};

  const uint4 zz = make_uint4(0,0,0,0);
  for (int k0 = 0; k0 < K; k0 += 32){
    __syncthreads();
    {
      bool av = (bm + sr) < M;
      size_t ga = (size_t)(bm + sr)*K + k0 + sc0;
      uint4 a0 = av ? *(const uint4*)(Ah + ga)     : zz;
      uint4 a1 = av ? *(const uint4*)(Ah + ga + 8) : zz;
      uint4 a2 = av ? *(const uint4*)(Al + ga)     : zz;
      uint4 a3 = av ? *(const uint4*)(Al + ga + 8) : zz;
      size_t gb = (size_t)(bn + sr)*K + k0 + sc0;
      uint4 b0 = *(const uint4*)(BTh + gb);
      uint4 b1 = *(const uint4*)(BTh + gb + 8);
      uint4 b2 = *(const uint4*)(BTl + gb);
      uint4 b3 = *(const uint4*)(BTl + gb + 8);
      int lo = sr*LDST + sc0;
      *(uint4*)&LAh[lo] = a0; *(uint4*)&LAh[lo+8] = a1;
      *(uint4*)&LAl[lo] = a2; *(uint4*)&LAl[lo+8] = a3;
      *(uint4*)&LBh[lo] = b0; *(uint4*)&LBh[lo+8] = b1;
      *(uint4*)&LBl[lo] = b2; *(uint4*)&LBl[lo+8] = b3;
    }
    __syncthreads();
    bf16x8 ah[4], al[4], bh[4], bl[4];
#pragma unroll
    for (int ai=0; ai<4; ++ai){
      int off = (wr*64 + ai*16 + l15)*LDST + kb*8;
      ah[ai] = *(const bf16x8*)&LAh[off];
      al[ai] = *(const bf16x8*)&LAl[off];
    }
#pragma unroll
    for (int bj=0; bj<4; ++bj){
      int off = (wc*64 + bj*16 + l15)*LDST + kb*8;
      bh[bj] = *(const bf16x8*)&LBh[off];
      bl[bj] = *(const bf16x8*)&LBl[off];
    }
#pragma unroll
    for (int ai=0; ai<4; ++ai)
#pragma unroll
      for (int bj=0; bj<4; ++bj){
        acc[ai][bj] = __builtin_amdgcn_mfma_f32_16x16x32_bf16(ah[ai], bh[bj], acc[ai][bj], 0,0,0);
        acc[ai][bj] = __builtin_amdgcn_mfma_f32_16x16x32_bf16(ah[ai], bl[bj], acc[ai][bj], 0,0,0);
        acc[ai][bj] = __builtin_amdgcn_mfma_f32_16x16x32_bf16(al[ai], bh[bj], acc[ai][bj], 0,0,0);
      }
  }
#pragma unroll
  for (int ai=0; ai<4; ++ai){
#pragma unroll
    for (int bj=0; bj<4; ++bj){
      int col = bn + wc*64 + bj*16 + l15;
      float bv = bias ? bias[col] : 0.f;
#pragma unroll
      for (int r=0; r<4; ++r){
        int row = bm + wr*64 + ai*16 + kb*4 + r;
        if (row < M){
          float v = acc[ai][bj][r] + bv;
          if (accum) v += C[(size_t)row*N + col];
          C[(size_t)row*N + col] = v;
        }
      }
    }
  }
}

// ---------------- split-bf16 MFMA GEMM: fp32 A, split during staging (XCD-swizzled) ----------------
__global__ __launch_bounds__(256) void gemm_sbf_kernel(
    const float* __restrict__ A,
    const unsigned short* __restrict__ BTh, const unsigned short* __restrict__ BTl,
    const float* __restrict__ bias, float* __restrict__ C,
    int M, int N, int K, int relu)
{
  __shared__ unsigned short LAh[128*LDST], LAl[128*LDST], LBh[128*LDST], LBl[128*LDST];
  const int t = threadIdx.x;
  const int nwg = gridDim.x * gridDim.y;
  const int orig = blockIdx.y * gridDim.x + blockIdx.x;
  const int wgid = xcd_swz(orig, nwg);
  const int bxi = wgid % gridDim.x, byi = wgid / gridDim.x;
  const int bm = byi << 7, bn = bxi << 7;
  const int wid = t >> 6, lane = t & 63;
  const int wr = wid >> 1, wc = wid & 1;
  const int l15 = lane & 15, kb = lane >> 4;
  const int sr = t >> 1, sc0 = (t & 1) << 4;
  f32x4 acc[4][4];
#pragma unroll
  for (int i=0;i<4;++i)
#pragma unroll
    for (int j=0;j<4;++j) acc[i][j] = (f32x4){0.f,0.f,0.f,0.f};

  for (int k0 = 0; k0 < K; k0 += 32){
    __syncthreads();
    {
      const float* ap = A + (size_t)(bm + sr)*K + k0 + sc0;
      float va[16];
      *(float4*)&va[0]  = ((const float4*)ap)[0];
      *(float4*)&va[4]  = ((const float4*)ap)[1];
      *(float4*)&va[8]  = ((const float4*)ap)[2];
      *(float4*)&va[12] = ((const float4*)ap)[3];
      int lo = sr*LDST + sc0;
      unsigned* dh = (unsigned*)&LAh[lo];
      unsigned* dl = (unsigned*)&LAl[lo];
#pragma unroll
      for (int q=0;q<8;++q){
        unsigned short h0,l0,h1,l1;
        split2(va[2*q],   h0, l0);
        split2(va[2*q+1], h1, l1);
        dh[q] = (unsigned)h0 | ((unsigned)h1 << 16);
        dl[q] = (unsigned)l0 | ((unsigned)l1 << 16);
      }
      size_t gb = (size_t)(bn + sr)*K + k0 + sc0;
      uint4 b0 = *(const uint4*)(BTh + gb);
      uint4 b1 = *(const uint4*)(BTh + gb + 8);
      uint4 b2 = *(const uint4*)(BTl + gb);
      uint4 b3 = *(const uint4*)(BTl + gb + 8);
      *(uint4*)&LBh[lo] = b0; *(uint4*)&LBh[lo+8] = b1;
      *(uint4*)&LBl[lo] = b2; *(uint4*)&LBl[lo+8] = b3;
    }
    __syncthreads();
    bf16x8 ah[4], al[4], bh[4], bl[4];
#pragma unroll
    for (int ai=0; ai<4; ++ai){
      int off = (wr*64 + ai*16 + l15)*LDST + kb*8;
      ah[ai] = *(const bf16x8*)&LAh[off];
      al[ai] = *(const bf16x8*)&LAl[off];
    }
#pragma unroll
    for (int bj=0; bj<4; ++bj){
      int off = (wc*64 + bj*16 + l15)*LDST + kb*8;
      bh[bj] = *(const bf16x8*)&LBh[off];
      bl[bj] = *(const bf16x8*)&LBl[off];
    }
#pragma unroll
    for (int ai=0; ai<4; ++ai)
#pragma unroll
      for (int bj=0; bj<4; ++bj){
        acc[ai][bj] = __builtin_amdgcn_mfma_f32_16x16x32_bf16(ah[ai], bh[bj], acc[ai][bj], 0,0,0);
        acc[ai][bj] = __builtin_amdgcn_mfma_f32_16x16x32_bf16(ah[ai], bl[bj], acc[ai][bj], 0,0,0);
        acc[ai][bj] = __builtin_amdgcn_mfma_f32_16x16x32_bf16(al[ai], bh[bj], acc[ai][bj], 0,0,0);
      }
  }
#pragma unroll
  for (int ai=0; ai<4; ++ai){
#pragma unroll
    for (int bj=0; bj<4; ++bj){
      int col = bn + wc*64 + bj*16 + l15;
      float bv = bias ? bias[col] : 0.f;
#pragma unroll
      for (int r=0; r<4; ++r){
        int row = bm + wr*64 + ai*16 + kb*4 + r;
        float v = acc[ai][bj][r] + bv;
        if (relu) v = fmaxf(v, 0.f);
        C[(size_t)row*N + col] = v;
      }
    }
  }
}

// -------- weights: fp32 [K][N] -> bf16 pair planes [N][K] (transposed)
__global__ void wt_split_T_kernel(const float* __restrict__ W,
                                  unsigned short* __restrict__ BTh,
                                  unsigned short* __restrict__ BTl, int K, int N)
{
  int idx = blockIdx.x*256 + threadIdx.x;
  if (idx >= N*K) return;
  int n = idx / K, k = idx - n*K;
  unsigned short h, l;
  split2(W[(size_t)k*N + n], h, l);
  BTh[idx] = h; BTl[idx] = l;
}

// -------- ATT rows 255.. -> bf16 pair planes [16512][512] (zero tail rows)
__global__ void att_split_kernel(const float* __restrict__ ATT,
                                 unsigned short* __restrict__ Ah,
                                 unsigned short* __restrict__ Al)
{
  size_t i4 = (size_t)blockIdx.x*256 + threadIdx.x;
  size_t e = i4*4;
  int row = (int)(e >> 9);
  float4 v = make_float4(0.f,0.f,0.f,0.f);
  if (row < NROWS) v = *(const float4*)(ATT + (size_t)PADT*DIM + e);
  unsigned short h0,l0,h1,l1,h2,l2,h3,l3;
  split2(v.x,h0,l0); split2(v.y,h1,l1); split2(v.z,h2,l2); split2(v.w,h3,l3);
  uint2 uh, ul;
  uh.x = (unsigned)h0 | ((unsigned)h1<<16); uh.y = (unsigned)h2 | ((unsigned)h3<<16);
  ul.x = (unsigned)l0 | ((unsigned)l1<<16); ul.y = (unsigned)l2 | ((unsigned)l3<<16);
  *(uint2*)(Ah + e) = uh;
  *(uint2*)(Al + e) = ul;
}

// -------- LayerNorm -> padded bf16-pair planes Yh/Yl (16640x512, top 255 rows = 0)
__global__ __launch_bounds__(256) void ln_pad_sb_kernel(
    const float* __restrict__ X, const float* __restrict__ g,
    const float* __restrict__ b, unsigned short* __restrict__ Yh,
    unsigned short* __restrict__ Yl)
{
  int p = blockIdx.x;
  int t = threadIdx.x;
  size_t base = (size_t)p*DIM;
  if (p < PADT){
    Yh[base+t] = 0; Yh[base+t+256] = 0;
    Yl[base+t] = 0; Yl[base+t+256] = 0;
    return;
  }
  const float* xr = X + (size_t)(p-PADT)*DIM;
  float x0 = xr[t], x1 = xr[t+256];
  float s = x0 + x1, sq = x0*x0 + x1*x1;
  s = wsum(s); sq = wsum(sq);
  __shared__ float rs[4], rq[4];
  if ((t&63)==0){ rs[t>>6]=s; rq[t>>6]=sq; }
  __syncthreads();
  float S = rs[0]+rs[1]+rs[2]+rs[3];
  float SQ = rq[0]+rq[1]+rq[2]+rq[3];
  float mu = S * (1.f/DIM);
  float var = SQ * (1.f/DIM) - mu*mu;
  float r = rsqrtf(var + 1e-5f);
  float y0 = (x0-mu)*r*g[t]     + b[t];
  float y1 = (x1-mu)*r*g[t+256] + b[t+256];
  unsigned short h, l;
  split2(y0, h, l); Yh[base+t] = h;     Yl[base+t] = l;
  split2(y1, h, l); Yh[base+t+256] = h; Yl[base+t+256] = l;
}

// -------- landmark means: QL (scaled by 1/8), KL + KL planes; grid (256, 8), block 64
__global__ void landmarks_kernel(const float* __restrict__ QKV,
                                 float* __restrict__ QL, float* __restrict__ KL,
                                 unsigned short* __restrict__ KLh,
                                 unsigned short* __restrict__ KLl)
{
  int m = blockIdx.x, h = blockIdx.y, d = threadIdx.x;
  float sq = 0.f, sk = 0.f;
  const float* base = QKV + (size_t)(m*LCH)*1536 + (h<<6) + d;
  for (int j = 0; j < LCH; ++j){
    sq += base[0];
    sk += base[512];
    base += 1536;
  }
  size_t off = (((size_t)(h<<8)+m)<<6) + d;
  float klv = sk * (1.f/65.f);
  QL[off] = sq * (0.125f/65.f);
  KL[off] = klv;
  unsigned short hh, ll;
  split2(klv, hh, ll);
  KLh[off] = hh; KLl[off] = ll;
}

// -------- sim2 + softmax -> A2; grid (256, 8), block 256
__global__ __launch_bounds__(256) void sim2_kernel(
    const float* __restrict__ QL, const float* __restrict__ KL, float* __restrict__ A2)
{
  int m = blockIdx.x, h = blockIdx.y, n = threadIdx.x;
  __shared__ float ql[64];
  __shared__ float red[4];
  if (n < 64) ql[n] = QL[(((h<<8)+m)<<6) + n];
  __syncthreads();
  const float* kl = KL + (size_t)(((h<<8)+n)<<6);
  float s = 0.f;
#pragma unroll
  for (int d=0; d<64; ++d) s += ql[d]*kl[d];
  float mx = wmax(s);
  if ((n&63)==0) red[n>>6] = mx;
  __syncthreads();
  mx = fmaxf(fmaxf(red[0],red[1]), fmaxf(red[2],red[3]));
  float e = __expf(s - mx);
  float sm = wsum(e);
  __syncthreads();
  if ((n&63)==0) red[n>>6] = sm;
  __syncthreads();
  sm = red[0]+red[1]+red[2]+red[3];
  A2[((size_t)((h<<8)+m)<<8) + n] = e/sm;
}

// -------- abs row+col sums of A2 in one kernel; grid 4096, block 256
__global__ void crsum_kernel(const float* __restrict__ A2, float* __restrict__ CR)
{
  int b = blockIdx.x, t = threadIdx.x;
  float v;
  if (b < 2048){
    v = fabsf(A2[((size_t)b<<8) + t]);
  } else {
    int r = b - 2048;
    int h = r >> 8, n = r & 255;
    v = fabsf(A2[((size_t)h<<16) + (t<<8) + n]);
  }
  v = wsum(v);
  __shared__ float red[4];
  if ((t&63)==0) red[t>>6]=v;
  __syncthreads();
  if (t==0) CR[b] = red[0]+red[1]+red[2]+red[3];
}
__global__ void maxprod_kernel(const float* __restrict__ CR, float* __restrict__ SCAL)
{
  int t = threadIdx.x;
  float mc = -3e38f, mr = -3e38f;
  for (int i=t; i<2048; i+=256){ mc = fmaxf(mc, CR[i]); mr = fmaxf(mr, CR[2048+i]); }
  mc = wmax(mc); mr = wmax(mr);
  __shared__ float rc[4], rr[4];
  if ((t&63)==0){ rc[t>>6]=mc; rr[t>>6]=mr; }
  __syncthreads();
  if (t==0){
    float a = fmaxf(fmaxf(rc[0],rc[1]),fmaxf(rc[2],rc[3]));
    float b = fmaxf(fmaxf(rr[0],rr[1]),fmaxf(rr[2],rr[3]));
    SCAL[0] = 1.f/(a*b);
  }
}

// -------- seed planes: A2 rm planes; Z0 = scal*A2^T as rm + tp planes; zero BAR
__global__ void tsplit_kernel(const float* __restrict__ A2, const float* __restrict__ SCAL,
                              unsigned short* __restrict__ A2h, unsigned short* __restrict__ A2l,
                              unsigned short* __restrict__ Zrh, unsigned short* __restrict__ Zrl,
                              unsigned short* __restrict__ Zth, unsigned short* __restrict__ Ztl,
                              unsigned* __restrict__ BAR)
{
  int idx = blockIdx.x*256 + threadIdx.x;
  if (idx == 0) BAR[0] = 0u;
  int h = idx >> 16, rem = idx & 65535, m = rem >> 8, n = rem & 255;
  float a = A2[idx];
  unsigned short hh, ll;
  split2(a, hh, ll);
  A2h[idx] = hh; A2l[idx] = ll;
  float z = a * SCAL[0];
  split2(z, hh, ll);
  Zth[idx] = hh; Ztl[idx] = ll;
  size_t rmo = ((size_t)h<<16) + (n<<8) + m;
  Zrh[rmo] = hh; Zrl[rmo] = ll;
}

// -------- MFMA flash landmark attention (transposed): grid (65, 4, 8), block 256
__global__ __launch_bounds__(256) void lattn3_kernel(
    const float* __restrict__ QKV, const float* __restrict__ QL,
    float* __restrict__ PACC, float* __restrict__ PML)
{
  const int c = blockIdx.x, lg = blockIdx.y, h = blockIdx.z;
  const int t = threadIdx.x;
  const int w = t >> 6, lane = t & 63;
  const int l15 = lane & 15, kb = lane >> 4;
  __shared__ unsigned short LQh[64*AST], LQl[64*AST];
  __shared__ unsigned short LKh[64*AST], LKl[64*AST];
  __shared__ unsigned short LPh[64*AST], LPl[64*AST];
  const int sr = t >> 2, sc0 = (t & 3) << 4;
  {
    const float* qp = QL + (((size_t)(h*256 + lg*64 + sr)) << 6) + sc0;
    float va[16];
    *(float4*)&va[0]  = ((const float4*)qp)[0];
    *(float4*)&va[4]  = ((const float4*)qp)[1];
    *(float4*)&va[8]  = ((const float4*)qp)[2];
    *(float4*)&va[12] = ((const float4*)qp)[3];
    unsigned* dh = (unsigned*)&LQh[sr*AST + sc0];
    unsigned* dl = (unsigned*)&LQl[sr*AST + sc0];
#pragma unroll
    for (int q=0;q<8;++q){
      unsigned short h0,l0,h1,l1;
      split2(va[2*q],   h0, l0);
      split2(va[2*q+1], h1, l1);
      dh[q] = (unsigned)h0 | ((unsigned)h1 << 16);
      dl[q] = (unsigned)l0 | ((unsigned)l1 << 16);
    }
  }
  float m = -3e38f, l = 0.f;
  f32x4 oacc[4];
#pragma unroll
  for (int i=0;i<4;++i) oacc[i] = (f32x4){0.f,0.f,0.f,0.f};

  for (int s = 0; s < 4; ++s){
    const int kbase = c*256 + s*64;
    __syncthreads();
    {
      const float* kp = QKV + (size_t)(kbase + sr)*1536 + 512 + (h<<6) + sc0;
      float va[16];
      *(float4*)&va[0]  = ((const float4*)kp)[0];
      *(float4*)&va[4]  = ((const float4*)kp)[1];
      *(float4*)&va[8]  = ((const float4*)kp)[2];
      *(float4*)&va[12] = ((const float4*)kp)[3];
      unsigned* dh = (unsigned*)&LKh[sr*AST + sc0];
      unsigned* dl = (unsigned*)&LKl[sr*AST + sc0];
#pragma unroll
      for (int q=0;q<8;++q){
        unsigned short h0,l0,h1,l1;
        split2(va[2*q],   h0, l0);
        split2(va[2*q+1], h1, l1);
        dh[q] = (unsigned)h0 | ((unsigned)h1 << 16);
        dl[q] = (unsigned)l0 | ((unsigned)l1 << 16);
      }
    }
    __syncthreads();
    f32x4 sacc[4];
#pragma unroll
    for (int i=0;i<4;++i) sacc[i] = (f32x4){0.f,0.f,0.f,0.f};
    __builtin_amdgcn_s_setprio(1);
#pragma unroll
    for (int ks = 0; ks < 2; ++ks){
      int qoff = (w*16 + l15)*AST + ks*32 + kb*8;
      bf16x8 bh = *(const bf16x8*)&LQh[qoff];
      bf16x8 bl = *(const bf16x8*)&LQl[qoff];
#pragma unroll
      for (int mi=0; mi<4; ++mi){
        int aoff = (mi*16 + l15)*AST + ks*32 + kb*8;
        bf16x8 ah = *(const bf16x8*)&LKh[aoff];
        bf16x8 al = *(const bf16x8*)&LKl[aoff];
        sacc[mi] = __builtin_amdgcn_mfma_f32_16x16x32_bf16(ah, bh, sacc[mi], 0,0,0);
        sacc[mi] = __builtin_amdgcn_mfma_f32_16x16x32_bf16(ah, bl, sacc[mi], 0,0,0);
        sacc[mi] = __builtin_amdgcn_mfma_f32_16x16x32_bf16(al, bh, sacc[mi], 0,0,0);
      }
    }
    __builtin_amdgcn_s_setprio(0);
    float tm = -3e38f;
#pragma unroll
    for (int mi=0;mi<4;++mi)
#pragma unroll
      for (int e=0;e<4;++e) tm = fmaxf(tm, sacc[mi][e]);
    tm = fmaxf(tm, __shfl_xor(tm, 16));
    tm = fmaxf(tm, __shfl_xor(tm, 32));
    float Mn = fmaxf(m, tm);
    float sc = __expf(m - Mn);
    float ts = 0.f;
    float p[4][4];
#pragma unroll
    for (int mi=0;mi<4;++mi)
#pragma unroll
      for (int e=0;e<4;++e){
        float pv = __expf(sacc[mi][e] - Mn);
        p[mi][e] = pv; ts += pv;
      }
    ts += __shfl_xor(ts, 16);
    ts += __shfl_xor(ts, 32);
    l = l*sc + ts;
    m = Mn;
#pragma unroll
    for (int mi=0;mi<4;++mi)
#pragma unroll
      for (int e=0;e<4;++e) oacc[mi][e] *= sc;
#pragma unroll
    for (int mi=0;mi<4;++mi){
      unsigned short h4[4], l4[4];
#pragma unroll
      for (int e=0;e<4;++e) split2(p[mi][e], h4[e], l4[e]);
      uint2 uh, ul;
      uh.x = (unsigned)h4[0] | ((unsigned)h4[1]<<16);
      uh.y = (unsigned)h4[2] | ((unsigned)h4[3]<<16);
      ul.x = (unsigned)l4[0] | ((unsigned)l4[1]<<16);
      ul.y = (unsigned)l4[2] | ((unsigned)l4[3]<<16);
      int po = (w*16 + l15)*AST + mi*16 + kb*4;
      *(uint2*)&LPh[po] = uh;
      *(uint2*)&LPl[po] = ul;
    }
    __syncthreads();
    {
      const float* vp = QKV + (size_t)(kbase + sr)*1536 + 1024 + (h<<6) + sc0;
      float va[16];
      *(float4*)&va[0]  = ((const float4*)vp)[0];
      *(float4*)&va[4]  = ((const float4*)vp)[1];
      *(float4*)&va[8]  = ((const float4*)vp)[2];
      *(float4*)&va[12] = ((const float4*)vp)[3];
#pragma unroll
      for (int i=0;i<16;++i){
        unsigned short hh, ll;
        split2(va[i], hh, ll);
        LKh[(sc0+i)*AST + sr] = hh;
        LKl[(sc0+i)*AST + sr] = ll;
      }
    }
    __syncthreads();
    __builtin_amdgcn_s_setprio(1);
#pragma unroll
    for (int ks = 0; ks < 2; ++ks){
      int poff = (w*16 + l15)*AST + ks*32 + kb*8;
      bf16x8 pbh = *(const bf16x8*)&LPh[poff];
      bf16x8 pbl = *(const bf16x8*)&LPl[poff];
#pragma unroll
      for (int mi=0; mi<4; ++mi){
        int aoff = (mi*16 + l15)*AST + ks*32 + kb*8;
        bf16x8 ah = *(const bf16x8*)&LKh[aoff];
        bf16x8 al = *(const bf16x8*)&LKl[aoff];
        oacc[mi] = __builtin_amdgcn_mfma_f32_16x16x32_bf16(ah, pbh, oacc[mi], 0,0,0);
        oacc[mi] = __builtin_amdgcn_mfma_f32_16x16x32_bf16(ah, pbl, oacc[mi], 0,0,0);
        oacc[mi] = __builtin_amdgcn_mfma_f32_16x16x32_bf16(al, pbh, oacc[mi], 0,0,0);
      }
    }
    __builtin_amdgcn_s_setprio(0);
  }
  size_t row = (size_t)(c*8 + h)*256 + lg*64 + w*16 + l15;
#pragma unroll
  for (int mi=0;mi<4;++mi){
    float4 o;
    o.x = oacc[mi][0]; o.y = oacc[mi][1]; o.z = oacc[mi][2]; o.w = oacc[mi][3];
    *(float4*)&PACC[row*64 + mi*16 + kb*4] = o;
  }
  if (kb == 0){
    PML[row*2 + 0] = m;
    PML[row*2 + 1] = l;
  }
}

// combine 65 chunks -> TMP^T bf16 planes [h][d][m]; grid 2048, block 64
__global__ void lattn_combine_kernel(const float* __restrict__ PACC,
                                     const float* __restrict__ PML,
                                     unsigned short* __restrict__ TMth,
                                     unsigned short* __restrict__ TMtl)
{
  int hm = blockIdx.x, d = threadIdx.x;
  int h = hm >> 8, m = hm & 255;
  float Mg = -3e38f;
#pragma unroll
  for (int c = 0; c < LCHUNK; ++c){
    size_t b = ((size_t)(c * 8 + h) * 256 + m) * 2;
    Mg = fmaxf(Mg, PML[b]);
  }
  float Sg = 0.f, o = 0.f;
#pragma unroll 4
  for (int c = 0; c < LCHUNK; ++c){
    size_t b = ((size_t)(c * 8 + h) * 256 + m) * 2;
    float e = __expf(PML[b] - Mg);
    Sg += PML[b+1] * e;
    o += PACC[((size_t)(c * 8 + h) * 256 + m) * 64 + d] * e;
  }
  unsigned short hh, ll;
  split2(o / Sg, hh, ll);
  size_t off = (size_t)h*16384 + (size_t)d*256 + m;
  TMth[off] = hh; TMtl[off] = ll;
}

// -------- MFMA flash attn over landmarks (transposed): grid (257, 8), block 256
__global__ __launch_bounds__(256) void attn3_kernel(
    const float* __restrict__ QKV,
    const unsigned short* __restrict__ KLh, const unsigned short* __restrict__ KLl,
    const unsigned short* __restrict__ BMth, const unsigned short* __restrict__ BMtl,
    float* __restrict__ ATT)
{
  const int qb = blockIdx.x, h = blockIdx.y;
  const int t = threadIdx.x;
  const int w = t >> 6, lane = t & 63;
  const int l15 = lane & 15, kb = lane >> 4;
  __shared__ unsigned short LQh[64*AST], LQl[64*AST];
  __shared__ unsigned short LAh[64*AST], LAl[64*AST];
  __shared__ unsigned short LPh[64*AST], LPl[64*AST];
  {
    int r = t >> 2, kc = (t & 3) << 4;
    int row = qb*64 + r; if (row > NROWS-1) row = NROWS-1;
    const float* qp = QKV + (size_t)(PADT+row)*1536 + (h<<6) + kc;
    float va[16];
    *(float4*)&va[0]  = ((const float4*)qp)[0];
    *(float4*)&va[4]  = ((const float4*)qp)[1];
    *(float4*)&va[8]  = ((const float4*)qp)[2];
    *(float4*)&va[12] = ((const float4*)qp)[3];
    unsigned* dh = (unsigned*)&LQh[r*AST + kc];
    unsigned* dl = (unsigned*)&LQl[r*AST + kc];
#pragma unroll
    for (int q=0;q<8;++q){
      unsigned short h0,l0,h1,l1;
      split2(va[2*q]*0.125f,   h0, l0);
      split2(va[2*q+1]*0.125f, h1, l1);
      dh[q] = (unsigned)h0 | ((unsigned)h1 << 16);
      dl[q] = (unsigned)l0 | ((unsigned)l1 << 16);
    }
  }
  float m = -3e38f, l = 0.f;
  f32x4 oacc[4];
#pragma unroll
  for (int i=0;i<4;++i) oacc[i] = (f32x4){0.f,0.f,0.f,0.f};
  const int sr = t >> 2, sc0 = (t & 3) << 4;

  for (int lt = 0; lt < 4; ++lt){
    __syncthreads();
    {
      size_t g = ((size_t)(h*256 + lt*64 + sr))*64 + sc0;
      uint4 vh0 = *(const uint4*)&KLh[g];
      uint4 vh1 = *(const uint4*)&KLh[g+8];
      uint4 vl0 = *(const uint4*)&KLl[g];
      uint4 vl1 = *(const uint4*)&KLl[g+8];
      int lo = sr*AST + sc0;
      *(uint4*)&LAh[lo]   = vh0;
      *(uint4*)&LAh[lo+8] = vh1;
      *(uint4*)&LAl[lo]   = vl0;
      *(uint4*)&LAl[lo+8] = vl1;
    }
    __syncthreads();
    f32x4 sacc[4];
#pragma unroll
    for (int i=0;i<4;++i) sacc[i] = (f32x4){0.f,0.f,0.f,0.f};
    __builtin_amdgcn_s_setprio(1);
#pragma unroll
    for (int ks = 0; ks < 2; ++ks){
      int qoff = (w*16 + l15)*AST + ks*32 + kb*8;
      bf16x8 bh = *(const bf16x8*)&LQh[qoff];
      bf16x8 bl = *(const bf16x8*)&LQl[qoff];
#pragma unroll
      for (int mi=0; mi<4; ++mi){
        int aoff = (mi*16 + l15)*AST + ks*32 + kb*8;
        bf16x8 ah = *(const bf16x8*)&LAh[aoff];
        bf16x8 al = *(const bf16x8*)&LAl[aoff];
        sacc[mi] = __builtin_amdgcn_mfma_f32_16x16x32_bf16(ah, bh, sacc[mi], 0,0,0);
        sacc[mi] = __builtin_amdgcn_mfma_f32_16x16x32_bf16(ah, bl, sacc[mi], 0,0,0);
        sacc[mi] = __builtin_amdgcn_mfma_f32_16x16x32_bf16(al, bh, sacc[mi], 0,0,0);
      }
    }
    __builtin_amdgcn_s_setprio(0);
    float tm = -3e38f;
#pragma unroll
    for (int mi=0;mi<4;++mi)
#pragma unroll
      for (int e=0;e<4;++e) tm = fmaxf(tm, sacc[mi][e]);
    tm = fmaxf(tm, __shfl_xor(tm, 16));
    tm = fmaxf(tm, __shfl_xor(tm, 32));
    float Mn = fmaxf(m, tm);
    float sc = __expf(m - Mn);
    float ts = 0.f;
    float p[4][4];
#pragma unroll
    for (int mi=0;mi<4;++mi)
#pragma unroll
      for (int e=0;e<4;++e){
        float pv = __expf(sacc[mi][e] - Mn);
        p[mi][e] = pv; ts += pv;
      }
    ts += __shfl_xor(ts, 16);
    ts += __shfl_xor(ts, 32);
    l = l*sc + ts;
    m = Mn;
#pragma unroll
    for (int mi=0;mi<4;++mi)
#pragma unroll
      for (int e=0;e<4;++e) oacc[mi][e] *= sc;
#pragma unroll
    for (int mi=0;mi<4;++mi){
      unsigned short h4[4], l4[4];
#pragma unroll
      for (int e=0;e<4;++e) split2(p[mi][e], h4[e], l4[e]);
      uint2 uh, ul;
      uh.x = (unsigned)h4[0] | ((unsigned)h4[1]<<16);
      uh.y = (unsigned)h4[2] | ((unsigned)h4[3]<<16);
      ul.x = (unsigned)l4[0] | ((unsigned)l4[1]<<16);
      ul.y = (unsigned)l4[2] | ((unsigned)l4[3]<<16);
      int po = (w*16 + l15)*AST + mi*16 + kb*4;
      *(uint2*)&LPh[po] = uh;
      *(uint2*)&LPl[po] = ul;
    }
    __syncthreads();
    {
      size_t g = ((size_t)(h*64 + sr))*256 + lt*64 + sc0;
      uint4 vh0 = *(const uint4*)&BMth[g];
      uint4 vh1 = *(const uint4*)&BMth[g+8];
      uint4 vl0 = *(const uint4*)&BMtl[g];
      uint4 vl1 = *(const uint4*)&BMtl[g+8];
      int lo = sr*AST + sc0;
      *(uint4*)&LAh[lo]   = vh0;
      *(uint4*)&LAh[lo+8] = vh1;
      *(uint4*)&LAl[lo]   = vl0;
      *(uint4*)&LAl[lo+8] = vl1;
    }
    __syncthreads();
    __builtin_amdgcn_s_setprio(1);
#pragma unroll
    for (int ks = 0; ks < 2; ++ks){
      int poff = (w*16 + l15)*AST + ks*32 + kb*8;
      bf16x8 pbh = *(const bf16x8*)&LPh[poff];
      bf16x8 pbl = *(const bf16x8*)&LPl[poff];
#pragma unroll
      for (int mi=0; mi<4; ++mi){
        int aoff = (mi*16 + l15)*AST + ks*32 + kb*8;
        bf16x8 ah = *(const bf16x8*)&LAh[aoff];
        bf16x8 al = *(const bf16x8*)&LAl[aoff];
        oacc[mi] = __builtin_amdgcn_mfma_f32_16x16x32_bf16(ah, pbh, oacc[mi], 0,0,0);
        oacc[mi] = __builtin_amdgcn_mfma_f32_16x16x32_bf16(ah, pbl, oacc[mi], 0,0,0);
        oacc[mi] = __builtin_amdgcn_mfma_f32_16x16x32_bf16(al, pbh, oacc[mi], 0,0,0);
      }
    }
    __builtin_amdgcn_s_setprio(0);
  }
  int row = qb*64 + w*16 + l15;
  if (row < NROWS){
    float inv = 1.f / l;
    float* op = ATT + (size_t)(PADT+row)*DIM + (h<<6) + kb*4;
#pragma unroll
    for (int mi=0;mi<4;++mi){
      float4 o;
      o.x = oacc[mi][0]*inv; o.y = oacc[mi][1]*inv;
      o.z = oacc[mi][2]*inv; o.w = oacc[mi][3]*inv;
      *(float4*)(op + mi*16) = o;
    }
  }
}

// -------- zero the SLACK rows after QKV so convres2 loads are unconditional
__global__ void zero_slack_kernel(float* __restrict__ QKV)
{
  int i = blockIdx.x*256 + threadIdx.x;
  QKV[(size_t)NPAD*1536 + i] = 0.f;
}

// -------- depthwise 33-tap conv residual, 4-row strips; grid (4097,2)
__global__ __launch_bounds__(256) void convres2_kernel(
    const float* __restrict__ QKV, const float* __restrict__ rw,
    float* __restrict__ ATT)
{
  const int t = threadIdx.x;
  const int c = blockIdx.y*256 + t;
  const int i0 = PADT + (blockIdx.x << 2);
  const int h = c >> 6;
  float w[33];
#pragma unroll
  for (int k=0;k<33;++k) w[k] = rw[h*33 + k];
  float acc[4] = {0.f,0.f,0.f,0.f};
  const float* vbase = QKV + (size_t)(i0-16)*1536 + 1024 + c;
#pragma unroll
  for (int rr=0; rr<36; ++rr){
    float v = vbase[(size_t)rr*1536];
#pragma unroll
    for (int k=0;k<4;++k){
      int tap = rr - k;
      if (tap >= 0 && tap <= 32) acc[k] += w[tap]*v;
    }
  }
#pragma unroll
  for (int k=0;k<4;++k){
    int i = i0 + k;
    if (i < NPAD) ATT[(size_t)i*DIM + c] += acc[k];
  }
}

// -------- PPEG prep: padded image PIM[134*134][512]
__global__ void pad_kernel(const float* __restrict__ X, float* __restrict__ PIM)
{
  int r = blockIdx.x;
  int c = blockIdx.y*256 + threadIdx.x;
  int py = r / 134, px = r - py*134;
  float v = 0.f;
  if (py>=3 && py<131 && px>=3 && px<131)
    v = X[(size_t)(1 + (py-3)*128 + (px-3))*512 + c];
  PIM[(size_t)r*512 + c] = v;
}

// -------- PPEG prep: transpose weights to [tap][channel]
__global__ void wtrans_kernel(const float* __restrict__ w7, const float* __restrict__ w5,
                              const float* __restrict__ w3, float* __restrict__ W7T,
                              float* __restrict__ W5T, float* __restrict__ W3T)
{
  int i = blockIdx.x;
  int c = blockIdx.y*256 + threadIdx.x;
  if (i < 49)      W7T[i*512+c]      = w7[c*49+i];
  else if (i < 74) W5T[(i-49)*512+c] = w5[c*25+(i-49)];
  else             W3T[(i-74)*512+c] = w3[c*9+(i-74)];
}

// -------- PPEG main: 4-pixel vertical strip per thread; grid (128,32,2)
__global__ __launch_bounds__(256) void ppeg2_kernel(
    const float* __restrict__ PIM, const float* __restrict__ W7T,
    const float* __restrict__ W5T, const float* __restrict__ W3T,
    const float* __restrict__ b7, const float* __restrict__ b5,
    const float* __restrict__ b3, float* __restrict__ X2)
{
  const int t = threadIdx.x;
  const int c = blockIdx.z*256 + t;
  const int x = blockIdx.x;
  const int y0 = blockIdx.y << 2;
  float w7r[49], w5r[25], w3r[9];
#pragma unroll
  for (int i=0;i<49;++i) w7r[i] = W7T[i*512 + c];
#pragma unroll
  for (int i=0;i<25;++i) w5r[i] = W5T[i*512 + c];
#pragma unroll
  for (int i=0;i<9;++i)  w3r[i] = W3T[i*512 + c];
  const float bsum = b7[c] + b5[c] + b3[c];
  float acc[4] = {bsum, bsum, bsum, bsum};
  const float* base = PIM + ((size_t)(y0*134 + x))*512 + c;
#pragma unroll
  for (int rr=0; rr<10; ++rr){
#pragma unroll
    for (int cc=0; cc<7; ++cc){
      float v = base[(size_t)(rr*134 + cc)*512];
#pragma unroll
      for (int k=0;k<4;++k){
        const int dy = rr - k - 3, dx = cc - 3;
        if (dy >= -3 && dy <= 3){
          acc[k] += w7r[(dy+3)*7 + (dx+3)] * v;
          if (dy >= -2 && dy <= 2 && dx >= -2 && dx <= 2)
            acc[k] += w5r[(dy+2)*5 + (dx+2)] * v;
          if (dy >= -1 && dy <= 1 && dx >= -1 && dx <= 1)
            acc[k] += w3r[(dy+1)*3 + (dx+1)] * v;
          if (dy == 0 && dx == 0) acc[k] += v;
        }
      }
    }
  }
#pragma unroll
  for (int k=0;k<4;++k)
    X2[(size_t)(1 + (y0+k)*128 + x)*512 + c] = acc[k];
}

__global__ void copy_row_kernel(const float* __restrict__ src, float* __restrict__ dst)
{
  dst[threadIdx.x] = src[threadIdx.x];
}

// -------- final: LN(row0) @ fc2 + b; 1 block 256
__global__ void final_kernel(const float* __restrict__ X, const float* __restrict__ g,
                             const float* __restrict__ b, const float* __restrict__ fw,
                             const float* __restrict__ fb, float* __restrict__ out)
{
  int t = threadIdx.x;
  float x0 = X[t], x1 = X[t+256];
  float s = x0 + x1, sq = x0*x0 + x1*x1;
  s = wsum(s); sq = wsum(sq);
  __shared__ float rs[4], rq[4];
  if ((t&63)==0){ rs[t>>6]=s; rq[t>>6]=sq; }
  __syncthreads();
  float S = rs[0]+rs[1]+rs[2]+rs[3];
  float SQ = rq[0]+rq[1]+rq[2]+rq[3];
  float mu = S*(1.f/DIM);
  float var = SQ*(1.f/DIM) - mu*mu;
  float r = rsqrtf(var + 1e-5f);
  float n0 = (x0-mu)*r*g[t]     + b[t];
  float n1 = (x1-mu)*r*g[t+256] + b[t+256];
  float p0 = n0*fw[t*2]   + n1*fw[(t+256)*2];
  float p1 = n0*fw[t*2+1] + n1*fw[(t+256)*2+1];
  p0 = wsum(p0); p1 = wsum(p1);
  __shared__ float r0[4], r1[4];
  if ((t&63)==0){ r0[t>>6]=p0; r1[t>>6]=p1; }
  __syncthreads();
  if (t==0){
    out[0] = r0[0]+r0[1]+r0[2]+r0[3] + fb[0];
    out[1] = r1[0]+r1[1]+r1[2]+r1[3] + fb[1];
  }
}

// ======================= host orchestration =======================
struct Bufs {
  float *Y, *QKV, *QL, *KL, *A2, *CR, *SCAL, *PACC, *PML, *W7T, *W5T, *W3T;
  unsigned short *Yh, *Yl, *ATh, *ATl, *qBTh, *qBTl, *oBTh, *oBTl, *fBTh, *fBTl;
  unsigned short *A2h, *A2l, *XZrh, *XZrl, *XZth, *XZtl, *Wth, *Wtl, *W2th, *W2tl;
  unsigned short *Z0rh, *Z0rl, *Z0th, *Z0tl, *Z1rh, *Z1rl, *Z1th, *Z1tl;
  unsigned short *TMth, *TMtl, *KLh, *KLl, *BMth, *BMtl;
};

static void attention_layer(float* X, const float* ln_g, const float* ln_b,
                            const float* qkv_w, const float* out_w, const float* out_b,
                            const float* res_w, Bufs& bf, hipStream_t stream)
{
  const long SP = 65536;
  unsigned* BAR = (unsigned*)(bf.SCAL + 4);
  wt_split_T_kernel<<<(1536*512)/256, 256, 0, stream>>>(qkv_w, bf.qBTh, bf.qBTl, 512, 1536);
  wt_split_T_kernel<<<(512*512)/256, 256, 0, stream>>>(out_w, bf.oBTh, bf.oBTl, 512, 512);
  ln_pad_sb_kernel<<<NPAD, 256, 0, stream>>>(X, ln_g, ln_b, bf.Yh, bf.Yl);
  gemm_sb_kernel<<<dim3(12,130),256,0,stream>>>(bf.Yh, bf.Yl, bf.qBTh, bf.qBTl,
      nullptr, bf.QKV, NPAD, 1536, 512, 0);
  landmarks_kernel<<<dim3(NL,HEADS),64,0,stream>>>(bf.QKV, bf.QL, bf.KL, bf.KLh, bf.KLl);
  sim2_kernel<<<dim3(NL,HEADS),256,0,stream>>>(bf.QL, bf.KL, bf.A2);
  crsum_kernel<<<4096,256,0,stream>>>(bf.A2, bf.CR);
  maxprod_kernel<<<1,256,0,stream>>>(bf.CR, bf.SCAL);
  tsplit_kernel<<<2048,256,0,stream>>>(bf.A2, bf.SCAL, bf.A2h, bf.A2l,
      bf.Z0rh, bf.Z0rl, bf.Z0th, bf.Z0tl, BAR);
  // fused 6-iteration Newton-Schulz chain (final Za -> Z0 buffers)
  pinv_fused_kernel<<<128,256,0,stream>>>(bf.A2h, bf.A2l,
      bf.XZrh, bf.XZrl, bf.XZth, bf.XZtl,
      bf.Wth, bf.Wtl, bf.W2th, bf.W2tl,
      bf.Z0rh, bf.Z0rl, bf.Z0th, bf.Z0tl,
      bf.Z1rh, bf.Z1rl, bf.Z1th, bf.Z1tl, BAR);
  lattn3_kernel<<<dim3(LCHUNK,4,HEADS),256,0,stream>>>(bf.QKV, bf.QL, bf.PACC, bf.PML);
  lattn_combine_kernel<<<2048,64,0,stream>>>(bf.PACC, bf.PML, bf.TMth, bf.TMtl);
  gemm64_sp_kernel<<<dim3(1,4,8),256,0,stream>>>(bf.Z0rh, bf.Z0rl, bf.TMth, bf.TMtl,
      nullptr,nullptr, nullptr,nullptr, nullptr,
      nullptr, nullptr, bf.BMth, bf.BMtl,
      256,64,256, SP, 16384L, 16384L, 1.f, 0.f, 0.f, 0.f);
  float* ATT = bf.Y;
  attn3_kernel<<<dim3(257,HEADS),256,0,stream>>>(bf.QKV, bf.KLh, bf.KLl,
      bf.BMth, bf.BMtl, ATT);
  convres2_kernel<<<dim3(4097,2),256,0,stream>>>(bf.QKV, res_w, ATT);
  att_split_kernel<<<8256,256,0,stream>>>(ATT, bf.ATh, bf.ATl);
  gemm_sb_kernel<<<dim3(4,129),256,0,stream>>>(bf.ATh, bf.ATl, bf.oBTh, bf.oBTl,
      out_b, X, NROWS, 512, 512, 1);
}

extern "C" void kernel_launch(void* const* d_in, const int* in_sizes, int n_in,
                              void* d_out, int out_size, void* d_ws, size_t ws_size,
                              hipStream_t stream)
{
  (void)in_sizes; (void)n_in; (void)out_size; (void)ws_size;
  const float* h       = (const float*)d_in[0];
  const float* fc1_w   = (const float*)d_in[1];
  const float* fc1_b   = (const float*)d_in[2];
  const float* cls     = (const float*)d_in[3];
  const float* l1_ln_g = (const float*)d_in[4];
  const float* l1_ln_b = (const float*)d_in[5];
  const float* l1_qkv_w= (const float*)d_in[6];
  const float* l1_out_w= (const float*)d_in[7];
  const float* l1_out_b= (const float*)d_in[8];
  const float* l1_res_w= (const float*)d_in[9];
  const float* conv7_w = (const float*)d_in[10];
  const float* conv7_b = (const float*)d_in[11];
  const float* conv5_w = (const float*)d_in[12];
  const float* conv5_b = (const float*)d_in[13];
  const float* conv3_w = (const float*)d_in[14];
  const float* conv3_b = (const float*)d_in[15];
  const float* l2_ln_g = (const float*)d_in[16];
  const float* l2_ln_b = (const float*)d_in[17];
  const float* l2_qkv_w= (const float*)d_in[18];
  const float* l2_out_w= (const float*)d_in[19];
  const float* l2_out_b= (const float*)d_in[20];
  const float* l2_res_w= (const float*)d_in[21];
  const float* norm_g  = (const float*)d_in[22];
  const float* norm_b  = (const float*)d_in[23];
  const float* fc2_w   = (const float*)d_in[24];
  const float* fc2_b   = (const float*)d_in[25];

  float* ws = (float*)d_ws;
  float* X   = ws;                 ws += (size_t)NROWS*DIM;
  float* X2  = ws;                 ws += (size_t)NROWS*DIM;
  Bufs bf;
  bf.Y    = ws;                    ws += (size_t)NPAD*DIM;
  bf.QKV  = ws;                    ws += (size_t)(NPAD+SLACK)*1536;
  bf.QL   = ws;                    ws += HEADS*NL*DH;
  bf.KL   = ws;                    ws += HEADS*NL*DH;
  bf.A2   = ws;                    ws += HEADS*NL*NL;
  bf.CR   = ws;                    ws += 4096;
  bf.SCAL = ws;                    ws += 8;
  bf.PACC = ws;                    ws += (size_t)LCHUNK*HEADS*NL*DH;
  bf.PML  = ws;                    ws += (size_t)LCHUNK*HEADS*NL*2;
  bf.W7T  = ws;                    ws += 49*512;
  bf.W5T  = ws;                    ws += 25*512;
  bf.W3T  = ws;                    ws += 9*512;
  unsigned short* us = (unsigned short*)ws;
  bf.Yh   = us;                    us += (size_t)NPAD*DIM;
  bf.Yl   = us;                    us += (size_t)NPAD*DIM;
  bf.ATh  = us;                    us += (size_t)16512*DIM;
  bf.ATl  = us;                    us += (size_t)16512*DIM;
  bf.qBTh = us;                    us += 1536*512;
  bf.qBTl = us;                    us += 1536*512;
  bf.oBTh = us;                    us += 512*512;
  bf.oBTl = us;                    us += 512*512;
  bf.fBTh = us;                    us += 512*2048;
  bf.fBTl = us;                    us += 512*2048;
  const size_t PL = (size_t)HEADS*NL*NL;
  bf.A2h  = us; us += PL;  bf.A2l  = us; us += PL;
  bf.XZrh = us; us += PL;  bf.XZrl = us; us += PL;
  bf.XZth = us; us += PL;  bf.XZtl = us; us += PL;
  bf.Wth  = us; us += PL;  bf.Wtl  = us; us += PL;
  bf.W2th = us; us += PL;  bf.W2tl = us; us += PL;
  bf.Z0rh = us; us += PL;  bf.Z0rl = us; us += PL;
  bf.Z0th = us; us += PL;  bf.Z0tl = us; us += PL;
  bf.Z1rh = us; us += PL;  bf.Z1rl = us; us += PL;
  bf.Z1th = us; us += PL;  bf.Z1tl = us; us += PL;
  bf.TMth = us; us += (size_t)HEADS*NL*DH;
  bf.TMtl = us; us += (size_t)HEADS*NL*DH;
  bf.KLh  = us; us += (size_t)HEADS*NL*DH;
  bf.KLl  = us; us += (size_t)HEADS*NL*DH;
  bf.BMth = us; us += (size_t)HEADS*NL*DH;
  bf.BMtl = us; us += (size_t)HEADS*NL*DH;
  float* PIM = bf.QKV;             // alias: QKV dead between the two layers

  zero_slack_kernel<<<(SLACK*1536)/256, 256, 0, stream>>>(bf.QKV);
  wtrans_kernel<<<dim3(83,2),256,0,stream>>>(conv7_w, conv5_w, conv3_w,
                                             bf.W7T, bf.W5T, bf.W3T);

  // fc1: split-bf16 MFMA, A split during staging (BK=32, XCD-swizzled)
  wt_split_T_kernel<<<(512*2048)/256, 256, 0, stream>>>(fc1_w, bf.fBTh, bf.fBTl, 2048, 512);
  gemm_sbf_kernel<<<dim3(4,128),256,0,stream>>>(h, bf.fBTh, bf.fBTl, fc1_b, X + DIM,
      16384, 512, 2048, 1);
  copy_row_kernel<<<1,512,0,stream>>>(cls, X);

  attention_layer(X, l1_ln_g, l1_ln_b, l1_qkv_w, l1_out_w, l1_out_b, l1_res_w, bf, stream);

  pad_kernel<<<dim3(17956,2),256,0,stream>>>(X, PIM);
  ppeg2_kernel<<<dim3(128,32,2),256,0,stream>>>(PIM, bf.W7T, bf.W5T, bf.W3T,
                                                conv7_b, conv5_b, conv3_b, X2);
  copy_row_kernel<<<1,512,0,stream>>>(X, X2);

  attention_layer(X2, l2_ln_g, l2_ln_b, l2_qkv_w, l2_out_w, l2_out_b, l2_res_w, bf, stream);

  final_kernel<<<1,256,0,stream>>>(X2, norm_g, norm_b, fc2_w, fc2_b, (float*)d_out);
}

// Round 23
// 1911.843 us; speedup vs baseline: 1.5474x; 1.5474x over previous
//
#include <hip/hip_runtime.h>
#include <cstddef>

#define NROWS 16385
#define NPAD  16640
#define PADT  255
#define DIM   512
#define HEADS 8
#define DH    64
#define NL    256
#define LCH   65
#define LCHUNK 65
#define SLACK 24
#define LDST  40   // padded LDS row stride (ushorts) for MFMA gemm tiles
#define AST   72   // attn3/lattn3 LDS row stride (ushorts); 144B = 16B-aligned rows

typedef short bf16x8 __attribute__((ext_vector_type(8)));
typedef float f32x4  __attribute__((ext_vector_type(4)));

__device__ __forceinline__ float wsum(float v){
#pragma unroll
  for (int o = 32; o; o >>= 1) v += __shfl_xor(v, o);
  return v;
}
__device__ __forceinline__ float wmax(float v){
#pragma unroll
  for (int o = 32; o; o >>= 1) v = fmaxf(v, __shfl_xor(v, o));
  return v;
}

// bijective XCD-chunked block remap (m204): dispatch order -> tile id so that
// consecutive tiles land on the same XCD's L2.
__device__ __forceinline__ int xcd_swz(int orig, int nwg){
  int q = nwg >> 3, r = nwg & 7;
  int x = orig & 7, j = orig >> 3;
  return (x < r ? x*(q+1) : r*(q+1) + (x-r)*q) + j;
}

// split fp32 -> (hi bf16, lo bf16) with RNE
__device__ __forceinline__ void split2(float x, unsigned short &h, unsigned short &l){
  unsigned ux = __float_as_uint(x);
  unsigned rh = (ux + 0x7FFFu + ((ux >> 16) & 1u)) >> 16;
  h = (unsigned short)rh;
  float fh = __uint_as_float(rh << 16);
  float r = x - fh;
  unsigned ur = __float_as_uint(r);
  unsigned rl = (ur + 0x7FFFu + ((ur >> 16) & 1u)) >> 16;
  l = (unsigned short)rl;
}
__device__ __forceinline__ float bf2f(unsigned short h){
  return __uint_as_float((unsigned)h << 16);
}

// ---------------- 64x64 batched MFMA GEMM on pre-split bf16 planes ----------------
// epilogue: v = aAcc*acc + cDiag*(row==col) + c1*rec(IB1) + c2*rec(IB2)
__global__ __launch_bounds__(256) void gemm64_sp_kernel(
    const unsigned short* __restrict__ Ah, const unsigned short* __restrict__ Al,
    const unsigned short* __restrict__ Bth, const unsigned short* __restrict__ Btl,
    const unsigned short* __restrict__ IB1h, const unsigned short* __restrict__ IB1l,
    const unsigned short* __restrict__ IB2h, const unsigned short* __restrict__ IB2l,
    float* __restrict__ Cf,
    unsigned short* __restrict__ Crh, unsigned short* __restrict__ Crl,
    unsigned short* __restrict__ Cth, unsigned short* __restrict__ Ctl,
    int M, int N, int K, long sA, long sB, long sC,
    float aAcc, float cDiag, float c1, float c2)
{
  size_t zo = (size_t)blockIdx.z;
  Ah  += zo*sA; Al  += zo*sA;
  Bth += zo*sB; Btl += zo*sB;
  if (IB1h){ IB1h += zo*sA; IB1l += zo*sA; }
  if (IB2h){ IB2h += zo*sA; IB2l += zo*sA; }
  if (Cf)  Cf  += zo*sC;
  if (Crh){ Crh += zo*sC; Crl += zo*sC; }
  if (Cth){ Cth += zo*sC; Ctl += zo*sC; }
  __shared__ unsigned short LAh[64*LDST], LAl[64*LDST], LBh[64*LDST], LBl[64*LDST];
  const int t = threadIdx.x;
  const int wid = t >> 6, lane = t & 63;
  const int wr = wid >> 1, wc = wid & 1;
  const int l15 = lane & 15, kb = lane >> 4;
  const int bm = blockIdx.y << 6, bn = blockIdx.x << 6;
  const int r4 = t >> 2, kc = (t & 3) << 3;
  f32x4 acc[2][2];
#pragma unroll
  for (int i=0;i<2;++i)
#pragma unroll
    for (int j=0;j<2;++j) acc[i][j] = (f32x4){0.f,0.f,0.f,0.f};

  for (int k0 = 0; k0 < K; k0 += 32){
    __syncthreads();
    {
      int lo = r4*LDST + kc;
      *(uint4*)&LAh[lo] = *(const uint4*)&Ah[(size_t)(bm+r4)*K + k0 + kc];
      *(uint4*)&LAl[lo] = *(const uint4*)&Al[(size_t)(bm+r4)*K + k0 + kc];
      *(uint4*)&LBh[lo] = *(const uint4*)&Bth[(size_t)(bn+r4)*K + k0 + kc];
      *(uint4*)&LBl[lo] = *(const uint4*)&Btl[(size_t)(bn+r4)*K + k0 + kc];
    }
    __syncthreads();
    bf16x8 ah[2], al[2], bh[2], bl[2];
#pragma unroll
    for (int r=0;r<2;++r){
      int off = (wr*32 + r*16 + l15)*LDST + kb*8;
      ah[r] = *(const bf16x8*)&LAh[off];
      al[r] = *(const bf16x8*)&LAl[off];
    }
#pragma unroll
    for (int c2v=0;c2v<2;++c2v){
      int off = (wc*32 + c2v*16 + l15)*LDST + kb*8;
      bh[c2v] = *(const bf16x8*)&LBh[off];
      bl[c2v] = *(const bf16x8*)&LBl[off];
    }
#pragma unroll
    for (int r=0;r<2;++r)
#pragma unroll
      for (int c2v=0;c2v<2;++c2v){
        acc[r][c2v] = __builtin_amdgcn_mfma_f32_16x16x32_bf16(ah[r], bh[c2v], acc[r][c2v], 0,0,0);
        acc[r][c2v] = __builtin_amdgcn_mfma_f32_16x16x32_bf16(ah[r], bl[c2v], acc[r][c2v], 0,0,0);
        acc[r][c2v] = __builtin_amdgcn_mfma_f32_16x16x32_bf16(al[r], bh[c2v], acc[r][c2v], 0,0,0);
      }
  }
#pragma unroll
  for (int r=0;r<2;++r){
#pragma unroll
    for (int c2v=0;c2v<2;++c2v){
      int col = bn + wc*32 + c2v*16 + l15;
      int rb  = bm + wr*32 + r*16 + kb*4;
      float v[4];
#pragma unroll
      for (int e=0;e<4;++e){
        float x = aAcc*acc[r][c2v][e];
        int row = rb + e;
        if (cDiag != 0.f && row == col) x += cDiag;
        if (IB1h){
          size_t io = (size_t)row*K + col;
          x += c1*(bf2f(IB1h[io]) + bf2f(IB1l[io]));
        }
        if (IB2h){
          size_t io = (size_t)row*K + col;
          x += c2*(bf2f(IB2h[io]) + bf2f(IB2l[io]));
        }
        v[e] = x;
      }
      if (Cf){
#pragma unroll
        for (int e=0;e<4;++e) Cf[(size_t)(rb+e)*N + col] = v[e];
      }
      if (Crh){
#pragma unroll
        for (int e=0;e<4;++e){
          unsigned short hh, ll;
          split2(v[e], hh, ll);
          Crh[(size_t)(rb+e)*N + col] = hh;
          Crl[(size_t)(rb+e)*N + col] = ll;
        }
      }
      if (Cth){
        unsigned short h4[4], l4[4];
#pragma unroll
        for (int e=0;e<4;++e) split2(v[e], h4[e], l4[e]);
        uint2 uh, ul;
        uh.x = (unsigned)h4[0] | ((unsigned)h4[1]<<16);
        uh.y = (unsigned)h4[2] | ((unsigned)h4[3]<<16);
        ul.x = (unsigned)l4[0] | ((unsigned)l4[1]<<16);
        ul.y = (unsigned)l4[2] | ((unsigned)l4[3]<<16);
        *(uint2*)&Cth[(size_t)col*M + rb] = uh;
        *(uint2*)&Ctl[(size_t)col*M + rb] = ul;
      }
    }
  }
}

// ---------------- split-bf16 MFMA GEMM: pre-split A planes (XCD-swizzled) ----------------
__global__ __launch_bounds__(256) void gemm_sb_kernel(
    const unsigned short* __restrict__ Ah, const unsigned short* __restrict__ Al,
    const unsigned short* __restrict__ BTh, const unsigned short* __restrict__ BTl,
    const float* __restrict__ bias, float* __restrict__ C,
    int M, int N, int K, int accum)
{
  __shared__ unsigned short LAh[128*LDST], LAl[128*LDST], LBh[128*LDST], LBl[128*LDST];
  const int t = threadIdx.x;
  const int nwg = gridDim.x * gridDim.y;
  const int orig = blockIdx.y * gridDim.x + blockIdx.x;
  const int wgid = xcd_swz(orig, nwg);
  const int bxi = wgid % gridDim.x, byi = wgid / gridDim.x;
  const int bm = byi << 7, bn = bxi << 7;
  const int wid = t >> 6, lane = t & 63;
  const int wr = wid >> 1, wc = wid & 1;
  const int l15 = lane & 15, kb = lane >> 4;
  const int sr = t >> 1, sc0 = (t & 1) << 4;
  f32x4 acc[4][4];
#pragma unroll
  for (int i=0;i<4;++i)
#pragma unroll
    for (int j=0;j<4;++j) acc[i][j] = (f32x4){0.f,0.f,0.f,0.f};

  const uint4 zz = make_uint4(0,0,0,0);
  for (int k0 = 0; k0 < K; k0 += 32){
    __syncthreads();
    {
      bool av = (bm + sr) < M;
      size_t ga = (size_t)(bm + sr)*K + k0 + sc0;
      uint4 a0 = av ? *(const uint4*)(Ah + ga)     : zz;
      uint4 a1 = av ? *(const uint4*)(Ah + ga + 8) : zz;
      uint4 a2 = av ? *(const uint4*)(Al + ga)     : zz;
      uint4 a3 = av ? *(const uint4*)(Al + ga + 8) : zz;
      size_t gb = (size_t)(bn + sr)*K + k0 + sc0;
      uint4 b0 = *(const uint4*)(BTh + gb);
      uint4 b1 = *(const uint4*)(BTh + gb + 8);
      uint4 b2 = *(const uint4*)(BTl + gb);
      uint4 b3 = *(const uint4*)(BTl + gb + 8);
      int lo = sr*LDST + sc0;
      *(uint4*)&LAh[lo] = a0; *(uint4*)&LAh[lo+8] = a1;
      *(uint4*)&LAl[lo] = a2; *(uint4*)&LAl[lo+8] = a3;
      *(uint4*)&LBh[lo] = b0; *(uint4*)&LBh[lo+8] = b1;
      *(uint4*)&LBl[lo] = b2; *(uint4*)&LBl[lo+8] = b3;
    }
    __syncthreads();
    bf16x8 ah[4], al[4], bh[4], bl[4];
#pragma unroll
    for (int ai=0; ai<4; ++ai){
      int off = (wr*64 + ai*16 + l15)*LDST + kb*8;
      ah[ai] = *(const bf16x8*)&LAh[off];
      al[ai] = *(const bf16x8*)&LAl[off];
    }
#pragma unroll
    for (int bj=0; bj<4; ++bj){
      int off = (wc*64 + bj*16 + l15)*LDST + kb*8;
      bh[bj] = *(const bf16x8*)&LBh[off];
      bl[bj] = *(const bf16x8*)&LBl[off];
    }
#pragma unroll
    for (int ai=0; ai<4; ++ai)
#pragma unroll
      for (int bj=0; bj<4; ++bj){
        acc[ai][bj] = __builtin_amdgcn_mfma_f32_16x16x32_bf16(ah[ai], bh[bj], acc[ai][bj], 0,0,0);
        acc[ai][bj] = __builtin_amdgcn_mfma_f32_16x16x32_bf16(ah[ai], bl[bj], acc[ai][bj], 0,0,0);
        acc[ai][bj] = __builtin_amdgcn_mfma_f32_16x16x32_bf16(al[ai], bh[bj], acc[ai][bj], 0,0,0);
      }
  }
#pragma unroll
  for (int ai=0; ai<4; ++ai){
#pragma unroll
    for (int bj=0; bj<4; ++bj){
      int col = bn + wc*64 + bj*16 + l15;
      float bv = bias ? bias[col] : 0.f;
#pragma unroll
      for (int r=0; r<4; ++r){
        int row = bm + wr*64 + ai*16 + kb*4 + r;
        if (row < M){
          float v = acc[ai][bj][r] + bv;
          if (accum) v += C[(size_t)row*N + col];
          C[(size_t)row*N + col] = v;
        }
      }
    }
  }
}

// ---------------- split-bf16 MFMA GEMM: fp32 A, split during staging (XCD-swizzled) ----------------
__global__ __launch_bounds__(256) void gemm_sbf_kernel(
    const float* __restrict__ A,
    const unsigned short* __restrict__ BTh, const unsigned short* __restrict__ BTl,
    const float* __restrict__ bias, float* __restrict__ C,
    int M, int N, int K, int relu)
{
  __shared__ unsigned short LAh[128*LDST], LAl[128*LDST], LBh[128*LDST], LBl[128*LDST];
  const int t = threadIdx.x;
  const int nwg = gridDim.x * gridDim.y;
  const int orig = blockIdx.y * gridDim.x + blockIdx.x;
  const int wgid = xcd_swz(orig, nwg);
  const int bxi = wgid % gridDim.x, byi = wgid / gridDim.x;
  const int bm = byi << 7, bn = bxi << 7;
  const int wid = t >> 6, lane = t & 63;
  const int wr = wid >> 1, wc = wid & 1;
  const int l15 = lane & 15, kb = lane >> 4;
  const int sr = t >> 1, sc0 = (t & 1) << 4;
  f32x4 acc[4][4];
#pragma unroll
  for (int i=0;i<4;++i)
#pragma unroll
    for (int j=0;j<4;++j) acc[i][j] = (f32x4){0.f,0.f,0.f,0.f};

  for (int k0 = 0; k0 < K; k0 += 32){
    __syncthreads();
    {
      const float* ap = A + (size_t)(bm + sr)*K + k0 + sc0;
      float va[16];
      *(float4*)&va[0]  = ((const float4*)ap)[0];
      *(float4*)&va[4]  = ((const float4*)ap)[1];
      *(float4*)&va[8]  = ((const float4*)ap)[2];
      *(float4*)&va[12] = ((const float4*)ap)[3];
      int lo = sr*LDST + sc0;
      unsigned* dh = (unsigned*)&LAh[lo];
      unsigned* dl = (unsigned*)&LAl[lo];
#pragma unroll
      for (int q=0;q<8;++q){
        unsigned short h0,l0,h1,l1;
        split2(va[2*q],   h0, l0);
        split2(va[2*q+1], h1, l1);
        dh[q] = (unsigned)h0 | ((unsigned)h1 << 16);
        dl[q] = (unsigned)l0 | ((unsigned)l1 << 16);
      }
      size_t gb = (size_t)(bn + sr)*K + k0 + sc0;
      uint4 b0 = *(const uint4*)(BTh + gb);
      uint4 b1 = *(const uint4*)(BTh + gb + 8);
      uint4 b2 = *(const uint4*)(BTl + gb);
      uint4 b3 = *(const uint4*)(BTl + gb + 8);
      *(uint4*)&LBh[lo] = b0; *(uint4*)&LBh[lo+8] = b1;
      *(uint4*)&LBl[lo] = b2; *(uint4*)&LBl[lo+8] = b3;
    }
    __syncthreads();
    bf16x8 ah[4], al[4], bh[4], bl[4];
#pragma unroll
    for (int ai=0; ai<4; ++ai){
      int off = (wr*64 + ai*16 + l15)*LDST + kb*8;
      ah[ai] = *(const bf16x8*)&LAh[off];
      al[ai] = *(const bf16x8*)&LAl[off];
    }
#pragma unroll
    for (int bj=0; bj<4; ++bj){
      int off = (wc*64 + bj*16 + l15)*LDST + kb*8;
      bh[bj] = *(const bf16x8*)&LBh[off];
      bl[bj] = *(const bf16x8*)&LBl[off];
    }
#pragma unroll
    for (int ai=0; ai<4; ++ai)
#pragma unroll
      for (int bj=0; bj<4; ++bj){
        acc[ai][bj] = __builtin_amdgcn_mfma_f32_16x16x32_bf16(ah[ai], bh[bj], acc[ai][bj], 0,0,0);
        acc[ai][bj] = __builtin_amdgcn_mfma_f32_16x16x32_bf16(ah[ai], bl[bj], acc[ai][bj], 0,0,0);
        acc[ai][bj] = __builtin_amdgcn_mfma_f32_16x16x32_bf16(al[ai], bh[bj], acc[ai][bj], 0,0,0);
      }
  }
#pragma unroll
  for (int ai=0; ai<4; ++ai){
#pragma unroll
    for (int bj=0; bj<4; ++bj){
      int col = bn + wc*64 + bj*16 + l15;
      float bv = bias ? bias[col] : 0.f;
#pragma unroll
      for (int r=0; r<4; ++r){
        int row = bm + wr*64 + ai*16 + kb*4 + r;
        float v = acc[ai][bj][r] + bv;
        if (relu) v = fmaxf(v, 0.f);
        C[(size_t)row*N + col] = v;
      }
    }
  }
}

// -------- weights: fp32 [K][N] -> bf16 pair planes [N][K] (transposed)
__global__ void wt_split_T_kernel(const float* __restrict__ W,
                                  unsigned short* __restrict__ BTh,
                                  unsigned short* __restrict__ BTl, int K, int N)
{
  int idx = blockIdx.x*256 + threadIdx.x;
  if (idx >= N*K) return;
  int n = idx / K, k = idx - n*K;
  unsigned short h, l;
  split2(W[(size_t)k*N + n], h, l);
  BTh[idx] = h; BTl[idx] = l;
}

// -------- ATT rows 255.. -> bf16 pair planes [16512][512] (zero tail rows)
__global__ void att_split_kernel(const float* __restrict__ ATT,
                                 unsigned short* __restrict__ Ah,
                                 unsigned short* __restrict__ Al)
{
  size_t i4 = (size_t)blockIdx.x*256 + threadIdx.x;
  size_t e = i4*4;
  int row = (int)(e >> 9);
  float4 v = make_float4(0.f,0.f,0.f,0.f);
  if (row < NROWS) v = *(const float4*)(ATT + (size_t)PADT*DIM + e);
  unsigned short h0,l0,h1,l1,h2,l2,h3,l3;
  split2(v.x,h0,l0); split2(v.y,h1,l1); split2(v.z,h2,l2); split2(v.w,h3,l3);
  uint2 uh, ul;
  uh.x = (unsigned)h0 | ((unsigned)h1<<16); uh.y = (unsigned)h2 | ((unsigned)h3<<16);
  ul.x = (unsigned)l0 | ((unsigned)l1<<16); ul.y = (unsigned)l2 | ((unsigned)l3<<16);
  *(uint2*)(Ah + e) = uh;
  *(uint2*)(Al + e) = ul;
}

// -------- LayerNorm -> padded bf16-pair planes Yh/Yl (16640x512, top 255 rows = 0)
__global__ __launch_bounds__(256) void ln_pad_sb_kernel(
    const float* __restrict__ X, const float* __restrict__ g,
    const float* __restrict__ b, unsigned short* __restrict__ Yh,
    unsigned short* __restrict__ Yl)
{
  int p = blockIdx.x;
  int t = threadIdx.x;
  size_t base = (size_t)p*DIM;
  if (p < PADT){
    Yh[base+t] = 0; Yh[base+t+256] = 0;
    Yl[base+t] = 0; Yl[base+t+256] = 0;
    return;
  }
  const float* xr = X + (size_t)(p-PADT)*DIM;
  float x0 = xr[t], x1 = xr[t+256];
  float s = x0 + x1, sq = x0*x0 + x1*x1;
  s = wsum(s); sq = wsum(sq);
  __shared__ float rs[4], rq[4];
  if ((t&63)==0){ rs[t>>6]=s; rq[t>>6]=sq; }
  __syncthreads();
  float S = rs[0]+rs[1]+rs[2]+rs[3];
  float SQ = rq[0]+rq[1]+rq[2]+rq[3];
  float mu = S * (1.f/DIM);
  float var = SQ * (1.f/DIM) - mu*mu;
  float r = rsqrtf(var + 1e-5f);
  float y0 = (x0-mu)*r*g[t]     + b[t];
  float y1 = (x1-mu)*r*g[t+256] + b[t+256];
  unsigned short h, l;
  split2(y0, h, l); Yh[base+t] = h;     Yl[base+t] = l;
  split2(y1, h, l); Yh[base+t+256] = h; Yl[base+t+256] = l;
}

// -------- landmark means: QL (scaled by 1/8), KL + KL planes; grid (256, 8), block 64
__global__ void landmarks_kernel(const float* __restrict__ QKV,
                                 float* __restrict__ QL, float* __restrict__ KL,
                                 unsigned short* __restrict__ KLh,
                                 unsigned short* __restrict__ KLl)
{
  int m = blockIdx.x, h = blockIdx.y, d = threadIdx.x;
  float sq = 0.f, sk = 0.f;
  const float* base = QKV + (size_t)(m*LCH)*1536 + (h<<6) + d;
  for (int j = 0; j < LCH; ++j){
    sq += base[0];
    sk += base[512];
    base += 1536;
  }
  size_t off = (((size_t)(h<<8)+m)<<6) + d;
  float klv = sk * (1.f/65.f);
  QL[off] = sq * (0.125f/65.f);
  KL[off] = klv;
  unsigned short hh, ll;
  split2(klv, hh, ll);
  KLh[off] = hh; KLl[off] = ll;
}

// -------- sim2 + softmax -> A2; grid (256, 8), block 256
__global__ __launch_bounds__(256) void sim2_kernel(
    const float* __restrict__ QL, const float* __restrict__ KL, float* __restrict__ A2)
{
  int m = blockIdx.x, h = blockIdx.y, n = threadIdx.x;
  __shared__ float ql[64];
  __shared__ float red[4];
  if (n < 64) ql[n] = QL[(((h<<8)+m)<<6) + n];
  __syncthreads();
  const float* kl = KL + (size_t)(((h<<8)+n)<<6);
  float s = 0.f;
#pragma unroll
  for (int d=0; d<64; ++d) s += ql[d]*kl[d];
  float mx = wmax(s);
  if ((n&63)==0) red[n>>6] = mx;
  __syncthreads();
  mx = fmaxf(fmaxf(red[0],red[1]), fmaxf(red[2],red[3]));
  float e = __expf(s - mx);
  float sm = wsum(e);
  __syncthreads();
  if ((n&63)==0) red[n>>6] = sm;
  __syncthreads();
  sm = red[0]+red[1]+red[2]+red[3];
  A2[((size_t)((h<<8)+m)<<8) + n] = e/sm;
}

// -------- abs row+col sums of A2 in one kernel; grid 4096, block 256
__global__ void crsum_kernel(const float* __restrict__ A2, float* __restrict__ CR)
{
  int b = blockIdx.x, t = threadIdx.x;
  float v;
  if (b < 2048){
    v = fabsf(A2[((size_t)b<<8) + t]);
  } else {
    int r = b - 2048;
    int h = r >> 8, n = r & 255;
    v = fabsf(A2[((size_t)h<<16) + (t<<8) + n]);
  }
  v = wsum(v);
  __shared__ float red[4];
  if ((t&63)==0) red[t>>6]=v;
  __syncthreads();
  if (t==0) CR[b] = red[0]+red[1]+red[2]+red[3];
}
__global__ void maxprod_kernel(const float* __restrict__ CR, float* __restrict__ SCAL)
{
  int t = threadIdx.x;
  float mc = -3e38f, mr = -3e38f;
  for (int i=t; i<2048; i+=256){ mc = fmaxf(mc, CR[i]); mr = fmaxf(mr, CR[2048+i]); }
  mc = wmax(mc); mr = wmax(mr);
  __shared__ float rc[4], rr[4];
  if ((t&63)==0){ rc[t>>6]=mc; rr[t>>6]=mr; }
  __syncthreads();
  if (t==0){
    float a = fmaxf(fmaxf(rc[0],rc[1]),fmaxf(rc[2],rc[3]));
    float b = fmaxf(fmaxf(rr[0],rr[1]),fmaxf(rr[2],rr[3]));
    SCAL[0] = 1.f/(a*b);
  }
}

// -------- seed planes: A2 rm planes; Z0 = scal*A2^T as rm + tp planes
__global__ void tsplit_kernel(const float* __restrict__ A2, const float* __restrict__ SCAL,
                              unsigned short* __restrict__ A2h, unsigned short* __restrict__ A2l,
                              unsigned short* __restrict__ Zrh, unsigned short* __restrict__ Zrl,
                              unsigned short* __restrict__ Zth, unsigned short* __restrict__ Ztl)
{
  int idx = blockIdx.x*256 + threadIdx.x;
  int h = idx >> 16, rem = idx & 65535, m = rem >> 8, n = rem & 255;
  float a = A2[idx];
  unsigned short hh, ll;
  split2(a, hh, ll);
  A2h[idx] = hh; A2l[idx] = ll;
  float z = a * SCAL[0];
  split2(z, hh, ll);
  Zth[idx] = hh; Ztl[idx] = ll;
  size_t rmo = ((size_t)h<<16) + (n<<8) + m;
  Zrh[rmo] = hh; Zrl[rmo] = ll;
}

// -------- MFMA flash landmark attention (transposed): grid (65, 4, 8), block 256
__global__ __launch_bounds__(256) void lattn3_kernel(
    const float* __restrict__ QKV, const float* __restrict__ QL,
    float* __restrict__ PACC, float* __restrict__ PML)
{
  const int c = blockIdx.x, lg = blockIdx.y, h = blockIdx.z;
  const int t = threadIdx.x;
  const int w = t >> 6, lane = t & 63;
  const int l15 = lane & 15, kb = lane >> 4;
  __shared__ unsigned short LQh[64*AST], LQl[64*AST];
  __shared__ unsigned short LKh[64*AST], LKl[64*AST];
  __shared__ unsigned short LPh[64*AST], LPl[64*AST];
  const int sr = t >> 2, sc0 = (t & 3) << 4;
  {
    const float* qp = QL + (((size_t)(h*256 + lg*64 + sr)) << 6) + sc0;
    float va[16];
    *(float4*)&va[0]  = ((const float4*)qp)[0];
    *(float4*)&va[4]  = ((const float4*)qp)[1];
    *(float4*)&va[8]  = ((const float4*)qp)[2];
    *(float4*)&va[12] = ((const float4*)qp)[3];
    unsigned* dh = (unsigned*)&LQh[sr*AST + sc0];
    unsigned* dl = (unsigned*)&LQl[sr*AST + sc0];
#pragma unroll
    for (int q=0;q<8;++q){
      unsigned short h0,l0,h1,l1;
      split2(va[2*q],   h0, l0);
      split2(va[2*q+1], h1, l1);
      dh[q] = (unsigned)h0 | ((unsigned)h1 << 16);
      dl[q] = (unsigned)l0 | ((unsigned)l1 << 16);
    }
  }
  float m = -3e38f, l = 0.f;
  f32x4 oacc[4];
#pragma unroll
  for (int i=0;i<4;++i) oacc[i] = (f32x4){0.f,0.f,0.f,0.f};

  for (int s = 0; s < 4; ++s){
    const int kbase = c*256 + s*64;
    __syncthreads();
    {
      const float* kp = QKV + (size_t)(kbase + sr)*1536 + 512 + (h<<6) + sc0;
      float va[16];
      *(float4*)&va[0]  = ((const float4*)kp)[0];
      *(float4*)&va[4]  = ((const float4*)kp)[1];
      *(float4*)&va[8]  = ((const float4*)kp)[2];
      *(float4*)&va[12] = ((const float4*)kp)[3];
      unsigned* dh = (unsigned*)&LKh[sr*AST + sc0];
      unsigned* dl = (unsigned*)&LKl[sr*AST + sc0];
#pragma unroll
      for (int q=0;q<8;++q){
        unsigned short h0,l0,h1,l1;
        split2(va[2*q],   h0, l0);
        split2(va[2*q+1], h1, l1);
        dh[q] = (unsigned)h0 | ((unsigned)h1 << 16);
        dl[q] = (unsigned)l0 | ((unsigned)l1 << 16);
      }
    }
    __syncthreads();
    f32x4 sacc[4];
#pragma unroll
    for (int i=0;i<4;++i) sacc[i] = (f32x4){0.f,0.f,0.f,0.f};
    __builtin_amdgcn_s_setprio(1);
#pragma unroll
    for (int ks = 0; ks < 2; ++ks){
      int qoff = (w*16 + l15)*AST + ks*32 + kb*8;
      bf16x8 bh = *(const bf16x8*)&LQh[qoff];
      bf16x8 bl = *(const bf16x8*)&LQl[qoff];
#pragma unroll
      for (int mi=0; mi<4; ++mi){
        int aoff = (mi*16 + l15)*AST + ks*32 + kb*8;
        bf16x8 ah = *(const bf16x8*)&LKh[aoff];
        bf16x8 al = *(const bf16x8*)&LKl[aoff];
        sacc[mi] = __builtin_amdgcn_mfma_f32_16x16x32_bf16(ah, bh, sacc[mi], 0,0,0);
        sacc[mi] = __builtin_amdgcn_mfma_f32_16x16x32_bf16(ah, bl, sacc[mi], 0,0,0);
        sacc[mi] = __builtin_amdgcn_mfma_f32_16x16x32_bf16(al, bh, sacc[mi], 0,0,0);
      }
    }
    __builtin_amdgcn_s_setprio(0);
    float tm = -3e38f;
#pragma unroll
    for (int mi=0;mi<4;++mi)
#pragma unroll
      for (int e=0;e<4;++e) tm = fmaxf(tm, sacc[mi][e]);
    tm = fmaxf(tm, __shfl_xor(tm, 16));
    tm = fmaxf(tm, __shfl_xor(tm, 32));
    float Mn = fmaxf(m, tm);
    float sc = __expf(m - Mn);
    float ts = 0.f;
    float p[4][4];
#pragma unroll
    for (int mi=0;mi<4;++mi)
#pragma unroll
      for (int e=0;e<4;++e){
        float pv = __expf(sacc[mi][e] - Mn);
        p[mi][e] = pv; ts += pv;
      }
    ts += __shfl_xor(ts, 16);
    ts += __shfl_xor(ts, 32);
    l = l*sc + ts;
    m = Mn;
#pragma unroll
    for (int mi=0;mi<4;++mi)
#pragma unroll
      for (int e=0;e<4;++e) oacc[mi][e] *= sc;
#pragma unroll
    for (int mi=0;mi<4;++mi){
      unsigned short h4[4], l4[4];
#pragma unroll
      for (int e=0;e<4;++e) split2(p[mi][e], h4[e], l4[e]);
      uint2 uh, ul;
      uh.x = (unsigned)h4[0] | ((unsigned)h4[1]<<16);
      uh.y = (unsigned)h4[2] | ((unsigned)h4[3]<<16);
      ul.x = (unsigned)l4[0] | ((unsigned)l4[1]<<16);
      ul.y = (unsigned)l4[2] | ((unsigned)l4[3]<<16);
      int po = (w*16 + l15)*AST + mi*16 + kb*4;
      *(uint2*)&LPh[po] = uh;
      *(uint2*)&LPl[po] = ul;
    }
    __syncthreads();
    {
      const float* vp = QKV + (size_t)(kbase + sr)*1536 + 1024 + (h<<6) + sc0;
      float va[16];
      *(float4*)&va[0]  = ((const float4*)vp)[0];
      *(float4*)&va[4]  = ((const float4*)vp)[1];
      *(float4*)&va[8]  = ((const float4*)vp)[2];
      *(float4*)&va[12] = ((const float4*)vp)[3];
#pragma unroll
      for (int i=0;i<16;++i){
        unsigned short hh, ll;
        split2(va[i], hh, ll);
        LKh[(sc0+i)*AST + sr] = hh;
        LKl[(sc0+i)*AST + sr] = ll;
      }
    }
    __syncthreads();
    __builtin_amdgcn_s_setprio(1);
#pragma unroll
    for (int ks = 0; ks < 2; ++ks){
      int poff = (w*16 + l15)*AST + ks*32 + kb*8;
      bf16x8 pbh = *(const bf16x8*)&LPh[poff];
      bf16x8 pbl = *(const bf16x8*)&LPl[poff];
#pragma unroll
      for (int mi=0; mi<4; ++mi){
        int aoff = (mi*16 + l15)*AST + ks*32 + kb*8;
        bf16x8 ah = *(const bf16x8*)&LKh[aoff];
        bf16x8 al = *(const bf16x8*)&LKl[aoff];
        oacc[mi] = __builtin_amdgcn_mfma_f32_16x16x32_bf16(ah, pbh, oacc[mi], 0,0,0);
        oacc[mi] = __builtin_amdgcn_mfma_f32_16x16x32_bf16(ah, pbl, oacc[mi], 0,0,0);
        oacc[mi] = __builtin_amdgcn_mfma_f32_16x16x32_bf16(al, pbh, oacc[mi], 0,0,0);
      }
    }
    __builtin_amdgcn_s_setprio(0);
  }
  size_t row = (size_t)(c*8 + h)*256 + lg*64 + w*16 + l15;
#pragma unroll
  for (int mi=0;mi<4;++mi){
    float4 o;
    o.x = oacc[mi][0]; o.y = oacc[mi][1]; o.z = oacc[mi][2]; o.w = oacc[mi][3];
    *(float4*)&PACC[row*64 + mi*16 + kb*4] = o;
  }
  if (kb == 0){
    PML[row*2 + 0] = m;
    PML[row*2 + 1] = l;
  }
}

// combine 65 chunks -> TMP^T bf16 planes [h][d][m]; grid 2048, block 64
__global__ void lattn_combine_kernel(const float* __restrict__ PACC,
                                     const float* __restrict__ PML,
                                     unsigned short* __restrict__ TMth,
                                     unsigned short* __restrict__ TMtl)
{
  int hm = blockIdx.x, d = threadIdx.x;
  int h = hm >> 8, m = hm & 255;
  float Mg = -3e38f;
#pragma unroll
  for (int c = 0; c < LCHUNK; ++c){
    size_t b = ((size_t)(c * 8 + h) * 256 + m) * 2;
    Mg = fmaxf(Mg, PML[b]);
  }
  float Sg = 0.f, o = 0.f;
#pragma unroll 4
  for (int c = 0; c < LCHUNK; ++c){
    size_t b = ((size_t)(c * 8 + h) * 256 + m) * 2;
    float e = __expf(PML[b] - Mg);
    Sg += PML[b+1] * e;
    o += PACC[((size_t)(c * 8 + h) * 256 + m) * 64 + d] * e;
  }
  unsigned short hh, ll;
  split2(o / Sg, hh, ll);
  size_t off = (size_t)h*16384 + (size_t)d*256 + m;
  TMth[off] = hh; TMtl[off] = ll;
}

// -------- MFMA flash attn over landmarks (transposed): grid (257, 8), block 256
__global__ __launch_bounds__(256) void attn3_kernel(
    const float* __restrict__ QKV,
    const unsigned short* __restrict__ KLh, const unsigned short* __restrict__ KLl,
    const unsigned short* __restrict__ BMth, const unsigned short* __restrict__ BMtl,
    float* __restrict__ ATT)
{
  const int qb = blockIdx.x, h = blockIdx.y;
  const int t = threadIdx.x;
  const int w = t >> 6, lane = t & 63;
  const int l15 = lane & 15, kb = lane >> 4;
  __shared__ unsigned short LQh[64*AST], LQl[64*AST];
  __shared__ unsigned short LAh[64*AST], LAl[64*AST];
  __shared__ unsigned short LPh[64*AST], LPl[64*AST];
  {
    int r = t >> 2, kc = (t & 3) << 4;
    int row = qb*64 + r; if (row > NROWS-1) row = NROWS-1;
    const float* qp = QKV + (size_t)(PADT+row)*1536 + (h<<6) + kc;
    float va[16];
    *(float4*)&va[0]  = ((const float4*)qp)[0];
    *(float4*)&va[4]  = ((const float4*)qp)[1];
    *(float4*)&va[8]  = ((const float4*)qp)[2];
    *(float4*)&va[12] = ((const float4*)qp)[3];
    unsigned* dh = (unsigned*)&LQh[r*AST + kc];
    unsigned* dl = (unsigned*)&LQl[r*AST + kc];
#pragma unroll
    for (int q=0;q<8;++q){
      unsigned short h0,l0,h1,l1;
      split2(va[2*q]*0.125f,   h0, l0);
      split2(va[2*q+1]*0.125f, h1, l1);
      dh[q] = (unsigned)h0 | ((unsigned)h1 << 16);
      dl[q] = (unsigned)l0 | ((unsigned)l1 << 16);
    }
  }
  float m = -3e38f, l = 0.f;
  f32x4 oacc[4];
#pragma unroll
  for (int i=0;i<4;++i) oacc[i] = (f32x4){0.f,0.f,0.f,0.f};
  const int sr = t >> 2, sc0 = (t & 3) << 4;

  for (int lt = 0; lt < 4; ++lt){
    __syncthreads();
    {
      size_t g = ((size_t)(h*256 + lt*64 + sr))*64 + sc0;
      uint4 vh0 = *(const uint4*)&KLh[g];
      uint4 vh1 = *(const uint4*)&KLh[g+8];
      uint4 vl0 = *(const uint4*)&KLl[g];
      uint4 vl1 = *(const uint4*)&KLl[g+8];
      int lo = sr*AST + sc0;
      *(uint4*)&LAh[lo]   = vh0;
      *(uint4*)&LAh[lo+8] = vh1;
      *(uint4*)&LAl[lo]   = vl0;
      *(uint4*)&LAl[lo+8] = vl1;
    }
    __syncthreads();
    f32x4 sacc[4];
#pragma unroll
    for (int i=0;i<4;++i) sacc[i] = (f32x4){0.f,0.f,0.f,0.f};
    __builtin_amdgcn_s_setprio(1);
#pragma unroll
    for (int ks = 0; ks < 2; ++ks){
      int qoff = (w*16 + l15)*AST + ks*32 + kb*8;
      bf16x8 bh = *(const bf16x8*)&LQh[qoff];
      bf16x8 bl = *(const bf16x8*)&LQl[qoff];
#pragma unroll
      for (int mi=0; mi<4; ++mi){
        int aoff = (mi*16 + l15)*AST + ks*32 + kb*8;
        bf16x8 ah = *(const bf16x8*)&LAh[aoff];
        bf16x8 al = *(const bf16x8*)&LAl[aoff];
        sacc[mi] = __builtin_amdgcn_mfma_f32_16x16x32_bf16(ah, bh, sacc[mi], 0,0,0);
        sacc[mi] = __builtin_amdgcn_mfma_f32_16x16x32_bf16(ah, bl, sacc[mi], 0,0,0);
        sacc[mi] = __builtin_amdgcn_mfma_f32_16x16x32_bf16(al, bh, sacc[mi], 0,0,0);
      }
    }
    __builtin_amdgcn_s_setprio(0);
    float tm = -3e38f;
#pragma unroll
    for (int mi=0;mi<4;++mi)
#pragma unroll
      for (int e=0;e<4;++e) tm = fmaxf(tm, sacc[mi][e]);
    tm = fmaxf(tm, __shfl_xor(tm, 16));
    tm = fmaxf(tm, __shfl_xor(tm, 32));
    float Mn = fmaxf(m, tm);
    float sc = __expf(m - Mn);
    float ts = 0.f;
    float p[4][4];
#pragma unroll
    for (int mi=0;mi<4;++mi)
#pragma unroll
      for (int e=0;e<4;++e){
        float pv = __expf(sacc[mi][e] - Mn);
        p[mi][e] = pv; ts += pv;
      }
    ts += __shfl_xor(ts, 16);
    ts += __shfl_xor(ts, 32);
    l = l*sc + ts;
    m = Mn;
#pragma unroll
    for (int mi=0;mi<4;++mi)
#pragma unroll
      for (int e=0;e<4;++e) oacc[mi][e] *= sc;
#pragma unroll
    for (int mi=0;mi<4;++mi){
      unsigned short h4[4], l4[4];
#pragma unroll
      for (int e=0;e<4;++e) split2(p[mi][e], h4[e], l4[e]);
      uint2 uh, ul;
      uh.x = (unsigned)h4[0] | ((unsigned)h4[1]<<16);
      uh.y = (unsigned)h4[2] | ((unsigned)h4[3]<<16);
      ul.x = (unsigned)l4[0] | ((unsigned)l4[1]<<16);
      ul.y = (unsigned)l4[2] | ((unsigned)l4[3]<<16);
      int po = (w*16 + l15)*AST + mi*16 + kb*4;
      *(uint2*)&LPh[po] = uh;
      *(uint2*)&LPl[po] = ul;
    }
    __syncthreads();
    {
      size_t g = ((size_t)(h*64 + sr))*256 + lt*64 + sc0;
      uint4 vh0 = *(const uint4*)&BMth[g];
      uint4 vh1 = *(const uint4*)&BMth[g+8];
      uint4 vl0 = *(const uint4*)&BMtl[g];
      uint4 vl1 = *(const uint4*)&BMtl[g+8];
      int lo = sr*AST + sc0;
      *(uint4*)&LAh[lo]   = vh0;
      *(uint4*)&LAh[lo+8] = vh1;
      *(uint4*)&LAl[lo]   = vl0;
      *(uint4*)&LAl[lo+8] = vl1;
    }
    __syncthreads();
    __builtin_amdgcn_s_setprio(1);
#pragma unroll
    for (int ks = 0; ks < 2; ++ks){
      int poff = (w*16 + l15)*AST + ks*32 + kb*8;
      bf16x8 pbh = *(const bf16x8*)&LPh[poff];
      bf16x8 pbl = *(const bf16x8*)&LPl[poff];
#pragma unroll
      for (int mi=0; mi<4; ++mi){
        int aoff = (mi*16 + l15)*AST + ks*32 + kb*8;
        bf16x8 ah = *(const bf16x8*)&LAh[aoff];
        bf16x8 al = *(const bf16x8*)&LAl[aoff];
        oacc[mi] = __builtin_amdgcn_mfma_f32_16x16x32_bf16(ah, pbh, oacc[mi], 0,0,0);
        oacc[mi] = __builtin_amdgcn_mfma_f32_16x16x32_bf16(ah, pbl, oacc[mi], 0,0,0);
        oacc[mi] = __builtin_amdgcn_mfma_f32_16x16x32_bf16(al, pbh, oacc[mi], 0,0,0);
      }
    }
    __builtin_amdgcn_s_setprio(0);
  }
  int row = qb*64 + w*16 + l15;
  if (row < NROWS){
    float inv = 1.f / l;
    float* op = ATT + (size_t)(PADT+row)*DIM + (h<<6) + kb*4;
#pragma unroll
    for (int mi=0;mi<4;++mi){
      float4 o;
      o.x = oacc[mi][0]*inv; o.y = oacc[mi][1]*inv;
      o.z = oacc[mi][2]*inv; o.w = oacc[mi][3]*inv;
      *(float4*)(op + mi*16) = o;
    }
  }
}

// -------- zero the SLACK rows after QKV so convres2 loads are unconditional
__global__ void zero_slack_kernel(float* __restrict__ QKV)
{
  int i = blockIdx.x*256 + threadIdx.x;
  QKV[(size_t)NPAD*1536 + i] = 0.f;
}

// -------- depthwise 33-tap conv residual, 4-row strips; grid (4097,2)
__global__ __launch_bounds__(256) void convres2_kernel(
    const float* __restrict__ QKV, const float* __restrict__ rw,
    float* __restrict__ ATT)
{
  const int t = threadIdx.x;
  const int c = blockIdx.y*256 + t;
  const int i0 = PADT + (blockIdx.x << 2);
  const int h = c >> 6;
  float w[33];
#pragma unroll
  for (int k=0;k<33;++k) w[k] = rw[h*33 + k];
  float acc[4] = {0.f,0.f,0.f,0.f};
  const float* vbase = QKV + (size_t)(i0-16)*1536 + 1024 + c;
#pragma unroll
  for (int rr=0; rr<36; ++rr){
    float v = vbase[(size_t)rr*1536];
#pragma unroll
    for (int k=0;k<4;++k){
      int tap = rr - k;
      if (tap >= 0 && tap <= 32) acc[k] += w[tap]*v;
    }
  }
#pragma unroll
  for (int k=0;k<4;++k){
    int i = i0 + k;
    if (i < NPAD) ATT[(size_t)i*DIM + c] += acc[k];
  }
}

// -------- PPEG prep: padded image PIM[134*134][512]
__global__ void pad_kernel(const float* __restrict__ X, float* __restrict__ PIM)
{
  int r = blockIdx.x;
  int c = blockIdx.y*256 + threadIdx.x;
  int py = r / 134, px = r - py*134;
  float v = 0.f;
  if (py>=3 && py<131 && px>=3 && px<131)
    v = X[(size_t)(1 + (py-3)*128 + (px-3))*512 + c];
  PIM[(size_t)r*512 + c] = v;
}

// -------- PPEG prep: transpose weights to [tap][channel]
__global__ void wtrans_kernel(const float* __restrict__ w7, const float* __restrict__ w5,
                              const float* __restrict__ w3, float* __restrict__ W7T,
                              float* __restrict__ W5T, float* __restrict__ W3T)
{
  int i = blockIdx.x;
  int c = blockIdx.y*256 + threadIdx.x;
  if (i < 49)      W7T[i*512+c]      = w7[c*49+i];
  else if (i < 74) W5T[(i-49)*512+c] = w5[c*25+(i-49)];
  else             W3T[(i-74)*512+c] = w3[c*9+(i-74)];
}

// -------- PPEG main: 4-pixel vertical strip per thread; grid (128,32,2)
__global__ __launch_bounds__(256) void ppeg2_kernel(
    const float* __restrict__ PIM, const float* __restrict__ W7T,
    const float* __restrict__ W5T, const float* __restrict__ W3T,
    const float* __restrict__ b7, const float* __restrict__ b5,
    const float* __restrict__ b3, float* __restrict__ X2)
{
  const int t = threadIdx.x;
  const int c = blockIdx.z*256 + t;
  const int x = blockIdx.x;
  const int y0 = blockIdx.y << 2;
  float w7r[49], w5r[25], w3r[9];
#pragma unroll
  for (int i=0;i<49;++i) w7r[i] = W7T[i*512 + c];
#pragma unroll
  for (int i=0;i<25;++i) w5r[i] = W5T[i*512 + c];
#pragma unroll
  for (int i=0;i<9;++i)  w3r[i] = W3T[i*512 + c];
  const float bsum = b7[c] + b5[c] + b3[c];
  float acc[4] = {bsum, bsum, bsum, bsum};
  const float* base = PIM + ((size_t)(y0*134 + x))*512 + c;
#pragma unroll
  for (int rr=0; rr<10; ++rr){
#pragma unroll
    for (int cc=0; cc<7; ++cc){
      float v = base[(size_t)(rr*134 + cc)*512];
#pragma unroll
      for (int k=0;k<4;++k){
        const int dy = rr - k - 3, dx = cc - 3;
        if (dy >= -3 && dy <= 3){
          acc[k] += w7r[(dy+3)*7 + (dx+3)] * v;
          if (dy >= -2 && dy <= 2 && dx >= -2 && dx <= 2)
            acc[k] += w5r[(dy+2)*5 + (dx+2)] * v;
          if (dy >= -1 && dy <= 1 && dx >= -1 && dx <= 1)
            acc[k] += w3r[(dy+1)*3 + (dx+1)] * v;
          if (dy == 0 && dx == 0) acc[k] += v;
        }
      }
    }
  }
#pragma unroll
  for (int k=0;k<4;++k)
    X2[(size_t)(1 + (y0+k)*128 + x)*512 + c] = acc[k];
}

__global__ void copy_row_kernel(const float* __restrict__ src, float* __restrict__ dst)
{
  dst[threadIdx.x] = src[threadIdx.x];
}

// -------- final: LN(row0) @ fc2 + b; 1 block 256
__global__ void final_kernel(const float* __restrict__ X, const float* __restrict__ g,
                             const float* __restrict__ b, const float* __restrict__ fw,
                             const float* __restrict__ fb, float* __restrict__ out)
{
  int t = threadIdx.x;
  float x0 = X[t], x1 = X[t+256];
  float s = x0 + x1, sq = x0*x0 + x1*x1;
  s = wsum(s); sq = wsum(sq);
  __shared__ float rs[4], rq[4];
  if ((t&63)==0){ rs[t>>6]=s; rq[t>>6]=sq; }
  __syncthreads();
  float S = rs[0]+rs[1]+rs[2]+rs[3];
  float SQ = rq[0]+rq[1]+rq[2]+rq[3];
  float mu = S*(1.f/DIM);
  float var = SQ*(1.f/DIM) - mu*mu;
  float r = rsqrtf(var + 1e-5f);
  float n0 = (x0-mu)*r*g[t]     + b[t];
  float n1 = (x1-mu)*r*g[t+256] + b[t+256];
  float p0 = n0*fw[t*2]   + n1*fw[(t+256)*2];
  float p1 = n0*fw[t*2+1] + n1*fw[(t+256)*2+1];
  p0 = wsum(p0); p1 = wsum(p1);
  __shared__ float r0[4], r1[4];
  if ((t&63)==0){ r0[t>>6]=p0; r1[t>>6]=p1; }
  __syncthreads();
  if (t==0){
    out[0] = r0[0]+r0[1]+r0[2]+r0[3] + fb[0];
    out[1] = r1[0]+r1[1]+r1[2]+r1[3] + fb[1];
  }
}

// ======================= host orchestration =======================
struct Bufs {
  float *Y, *QKV, *QL, *KL, *A2, *CR, *SCAL, *PACC, *PML, *W7T, *W5T, *W3T;
  unsigned short *Yh, *Yl, *ATh, *ATl, *qBTh, *qBTl, *oBTh, *oBTl, *fBTh, *fBTl;
  unsigned short *A2h, *A2l, *XZrh, *XZrl, *XZth, *XZtl, *Wth, *Wtl, *W2th, *W2tl;
  unsigned short *Z0rh, *Z0rl, *Z0th, *Z0tl, *Z1rh, *Z1rl, *Z1th, *Z1tl;
  unsigned short *TMth, *TMtl, *KLh, *KLl, *BMth, *BMtl;
};

static void attention_layer(float* X, const float* ln_g, const float* ln_b,
                            const float* qkv_w, const float* out_w, const float* out_b,
                            const float* res_w, Bufs& bf, hipStream_t stream)
{
  const long SP = 65536;
  wt_split_T_kernel<<<(1536*512)/256, 256, 0, stream>>>(qkv_w, bf.qBTh, bf.qBTl, 512, 1536);
  wt_split_T_kernel<<<(512*512)/256, 256, 0, stream>>>(out_w, bf.oBTh, bf.oBTl, 512, 512);
  ln_pad_sb_kernel<<<NPAD, 256, 0, stream>>>(X, ln_g, ln_b, bf.Yh, bf.Yl);
  gemm_sb_kernel<<<dim3(12,130),256,0,stream>>>(bf.Yh, bf.Yl, bf.qBTh, bf.qBTl,
      nullptr, bf.QKV, NPAD, 1536, 512, 0);
  landmarks_kernel<<<dim3(NL,HEADS),64,0,stream>>>(bf.QKV, bf.QL, bf.KL, bf.KLh, bf.KLl);
  sim2_kernel<<<dim3(NL,HEADS),256,0,stream>>>(bf.QL, bf.KL, bf.A2);
  crsum_kernel<<<4096,256,0,stream>>>(bf.A2, bf.CR);
  maxprod_kernel<<<1,256,0,stream>>>(bf.CR, bf.SCAL);
  tsplit_kernel<<<2048,256,0,stream>>>(bf.A2, bf.SCAL, bf.A2h, bf.A2l,
      bf.Z0rh, bf.Z0rl, bf.Z0th, bf.Z0tl);
  unsigned short *Zarh=bf.Z0rh, *Zarl=bf.Z0rl, *Zath=bf.Z0th, *Zatl=bf.Z0tl;
  unsigned short *Zbrh=bf.Z1rh, *Zbrl=bf.Z1rl, *Zbth=bf.Z1th, *Zbtl=bf.Z1tl;
  // Horner Newton-Schulz: M=A2@Za; W=7M-M2; W2=15M-MW; Zb=0.25(13Za-Za@W2)
  for (int it = 0; it < 6; ++it){
    gemm64_sp_kernel<<<dim3(4,4,8),256,0,stream>>>(bf.A2h, bf.A2l, Zath, Zatl,
        nullptr,nullptr, nullptr,nullptr, nullptr,
        bf.XZrh, bf.XZrl, bf.XZth, bf.XZtl,
        256,256,256, SP,SP,SP, 1.f, 0.f, 0.f, 0.f);
    gemm64_sp_kernel<<<dim3(4,4,8),256,0,stream>>>(bf.XZrh, bf.XZrl, bf.XZth, bf.XZtl,
        bf.XZrh, bf.XZrl, nullptr,nullptr, nullptr,
        nullptr, nullptr, bf.Wth, bf.Wtl,
        256,256,256, SP,SP,SP, -1.f, 0.f, 7.f, 0.f);
    gemm64_sp_kernel<<<dim3(4,4,8),256,0,stream>>>(bf.XZrh, bf.XZrl, bf.Wth, bf.Wtl,
        bf.XZrh, bf.XZrl, nullptr,nullptr, nullptr,
        nullptr, nullptr, bf.W2th, bf.W2tl,
        256,256,256, SP,SP,SP, -1.f, 0.f, 15.f, 0.f);
    gemm64_sp_kernel<<<dim3(4,4,8),256,0,stream>>>(Zarh, Zarl, bf.W2th, bf.W2tl,
        Zarh, Zarl, nullptr,nullptr, nullptr,
        Zbrh, Zbrl, Zbth, Zbtl,
        256,256,256, SP,SP,SP, -0.25f, 0.f, 3.25f, 0.f);
    unsigned short* tp;
    tp=Zarh; Zarh=Zbrh; Zbrh=tp;  tp=Zarl; Zarl=Zbrl; Zbrl=tp;
    tp=Zath; Zath=Zbth; Zbth=tp;  tp=Zatl; Zatl=Zbtl; Zbtl=tp;
  }
  lattn3_kernel<<<dim3(LCHUNK,4,HEADS),256,0,stream>>>(bf.QKV, bf.QL, bf.PACC, bf.PML);
  lattn_combine_kernel<<<2048,64,0,stream>>>(bf.PACC, bf.PML, bf.TMth, bf.TMtl);
  gemm64_sp_kernel<<<dim3(1,4,8),256,0,stream>>>(Zarh, Zarl, bf.TMth, bf.TMtl,
      nullptr,nullptr, nullptr,nullptr, nullptr,
      nullptr, nullptr, bf.BMth, bf.BMtl,
      256,64,256, SP, 16384L, 16384L, 1.f, 0.f, 0.f, 0.f);
  float* ATT = bf.Y;
  attn3_kernel<<<dim3(257,HEADS),256,0,stream>>>(bf.QKV, bf.KLh, bf.KLl,
      bf.BMth, bf.BMtl, ATT);
  convres2_kernel<<<dim3(4097,2),256,0,stream>>>(bf.QKV, res_w, ATT);
  att_split_kernel<<<8256,256,0,stream>>>(ATT, bf.ATh, bf.ATl);
  gemm_sb_kernel<<<dim3(4,129),256,0,stream>>>(bf.ATh, bf.ATl, bf.oBTh, bf.oBTl,
      out_b, X, NROWS, 512, 512, 1);
}

extern "C" void kernel_launch(void* const* d_in, const int* in_sizes, int n_in,
                              void* d_out, int out_size, void* d_ws, size_t ws_size,
                              hipStream_t stream)
{
  (void)in_sizes; (void)n_in; (void)out_size; (void)ws_size;
  const float* h       = (const float*)d_in[0];
  const float* fc1_w   = (const float*)d_in[1];
  const float* fc1_b   = (const float*)d_in[2];
  const float* cls     = (const float*)d_in[3];
  const float* l1_ln_g = (const float*)d_in[4];
  const float* l1_ln_b = (const float*)d_in[5];
  const float* l1_qkv_w= (const float*)d_in[6];
  const float* l1_out_w= (const float*)d_in[7];
  const float* l1_out_b= (const float*)d_in[8];
  const float* l1_res_w= (const float*)d_in[9];
  const float* conv7_w = (const float*)d_in[10];
  const float* conv7_b = (const float*)d_in[11];
  const float* conv5_w = (const float*)d_in[12];
  const float* conv5_b = (const float*)d_in[13];
  const float* conv3_w = (const float*)d_in[14];
  const float* conv3_b = (const float*)d_in[15];
  const float* l2_ln_g = (const float*)d_in[16];
  const float* l2_ln_b = (const float*)d_in[17];
  const float* l2_qkv_w= (const float*)d_in[18];
  const float* l2_out_w= (const float*)d_in[19];
  const float* l2_out_b= (const float*)d_in[20];
  const float* l2_res_w= (const float*)d_in[21];
  const float* norm_g  = (const float*)d_in[22];
  const float* norm_b  = (const float*)d_in[23];
  const float* fc2_w   = (const float*)d_in[24];
  const float* fc2_b   = (const float*)d_in[25];

  float* ws = (float*)d_ws;
  float* X   = ws;                 ws += (size_t)NROWS*DIM;
  float* X2  = ws;                 ws += (size_t)NROWS*DIM;
  Bufs bf;
  bf.Y    = ws;                    ws += (size_t)NPAD*DIM;
  bf.QKV  = ws;                    ws += (size_t)(NPAD+SLACK)*1536;
  bf.QL   = ws;                    ws += HEADS*NL*DH;
  bf.KL   = ws;                    ws += HEADS*NL*DH;
  bf.A2   = ws;                    ws += HEADS*NL*NL;
  bf.CR   = ws;                    ws += 4096;
  bf.SCAL = ws;                    ws += 8;
  bf.PACC = ws;                    ws += (size_t)LCHUNK*HEADS*NL*DH;
  bf.PML  = ws;                    ws += (size_t)LCHUNK*HEADS*NL*2;
  bf.W7T  = ws;                    ws += 49*512;
  bf.W5T  = ws;                    ws += 25*512;
  bf.W3T  = ws;                    ws += 9*512;
  unsigned short* us = (unsigned short*)ws;
  bf.Yh   = us;                    us += (size_t)NPAD*DIM;
  bf.Yl   = us;                    us += (size_t)NPAD*DIM;
  bf.ATh  = us;                    us += (size_t)16512*DIM;
  bf.ATl  = us;                    us += (size_t)16512*DIM;
  bf.qBTh = us;                    us += 1536*512;
  bf.qBTl = us;                    us += 1536*512;
  bf.oBTh = us;                    us += 512*512;
  bf.oBTl = us;                    us += 512*512;
  bf.fBTh = us;                    us += 512*2048;
  bf.fBTl = us;                    us += 512*2048;
  const size_t PL = (size_t)HEADS*NL*NL;
  bf.A2h  = us; us += PL;  bf.A2l  = us; us += PL;
  bf.XZrh = us; us += PL;  bf.XZrl = us; us += PL;
  bf.XZth = us; us += PL;  bf.XZtl = us; us += PL;
  bf.Wth  = us; us += PL;  bf.Wtl  = us; us += PL;
  bf.W2th = us; us += PL;  bf.W2tl = us; us += PL;
  bf.Z0rh = us; us += PL;  bf.Z0rl = us; us += PL;
  bf.Z0th = us; us += PL;  bf.Z0tl = us; us += PL;
  bf.Z1rh = us; us += PL;  bf.Z1rl = us; us += PL;
  bf.Z1th = us; us += PL;  bf.Z1tl = us; us += PL;
  bf.TMth = us; us += (size_t)HEADS*NL*DH;
  bf.TMtl = us; us += (size_t)HEADS*NL*DH;
  bf.KLh  = us; us += (size_t)HEADS*NL*DH;
  bf.KLl  = us; us += (size_t)HEADS*NL*DH;
  bf.BMth = us; us += (size_t)HEADS*NL*DH;
  bf.BMtl = us; us += (size_t)HEADS*NL*DH;
  float* PIM = bf.QKV;             // alias: QKV dead between the two layers

  zero_slack_kernel<<<(SLACK*1536)/256, 256, 0, stream>>>(bf.QKV);
  wtrans_kernel<<<dim3(83,2),256,0,stream>>>(conv7_w, conv5_w, conv3_w,
                                             bf.W7T, bf.W5T, bf.W3T);

  // fc1: split-bf16 MFMA, A split during staging (BK=32, XCD-swizzled)
  wt_split_T_kernel<<<(512*2048)/256, 256, 0, stream>>>(fc1_w, bf.fBTh, bf.fBTl, 2048, 512);
  gemm_sbf_kernel<<<dim3(4,128),256,0,stream>>>(h, bf.fBTh, bf.fBTl, fc1_b, X + DIM,
      16384, 512, 2048, 1);
  copy_row_kernel<<<1,512,0,stream>>>(cls, X);

  attention_layer(X, l1_ln_g, l1_ln_b, l1_qkv_w, l1_out_w, l1_out_b, l1_res_w, bf, stream);

  pad_kernel<<<dim3(17956,2),256,0,stream>>>(X, PIM);
  ppeg2_kernel<<<dim3(128,32,2),256,0,stream>>>(PIM, bf.W7T, bf.W5T, bf.W3T,
                                                conv7_b, conv5_b, conv3_b, X2);
  copy_row_kernel<<<1,512,0,stream>>>(X, X2);

  attention_layer(X2, l2_ln_g, l2_ln_b, l2_qkv_w, l2_out_w, l2_out_b, l2_res_w, bf, stream);

  final_kernel<<<1,256,0,stream>>>(X2, norm_g, norm_b, fc2_w, fc2_b, (float*)d_out);
}